// Round 1
// baseline (5289.943 us; speedup 1.0000x reference)
//
#include <hip/hip_runtime.h>
#include <hip/hip_bf16.h>

// ---------------- problem dims ----------------
#define TT 40
#define BB 64
#define LL 80
#define DD 256
#define HH 1024
#define G4H 4096
#define AA 18
#define KENC 1280   // [demo(256) | h(1024)]
#define KLSTM 2048  // [x(1024) | h(1024)]
#define KCOMB 1280  // [attn(1024) | obs(256)]
#define NB 128
#define NT 256
#define QSZ (TT*BB*AA)

typedef __bf16 bf16x8 __attribute__((ext_vector_type(8)));
typedef float  f32x4  __attribute__((ext_vector_type(4)));

// ---------------- workspace layout (bytes) ----------------
#define OFF_WENC   ((size_t)0)
#define OFF_WLSTM  (OFF_WENC  + (size_t)G4H*KENC*2)
#define OFF_WCOMB  (OFF_WLSTM + (size_t)G4H*KLSTM*2)
#define OFF_WMID   (OFF_WCOMB + (size_t)HH*KCOMB*2)
#define OFF_DEMO   (OFF_WMID  + (size_t)HH*HH*2)
#define OFF_STATE  (OFF_DEMO  + (size_t)LL*BB*DD*2)
#define OFF_ENC    (OFF_STATE + (size_t)TT*BB*DD*2)
#define OFF_HDEC   (OFF_ENC   + (size_t)BB*LL*HH*2)
#define OFF_MF     (OFF_HDEC  + (size_t)TT*BB*HH*2)
#define OFF_SCORED (OFF_MF    + (size_t)TT*BB*HH*2)
#define OFF_HF     (OFF_SCORED+ (size_t)BB*LL*4)
#define OFF_CF     (OFF_HF    + (size_t)BB*HH*4)
#define OFF_HB0    (OFF_CF    + (size_t)BB*HH*4)
#define OFF_HB1    (OFF_HB0   + (size_t)BB*HH*2)
#define OFF_XB     (OFF_HB1   + (size_t)BB*HH*2)
#define OFF_ATTN   (OFF_XB    + (size_t)BB*HH*2)
#define OFF_BAR    (OFF_ATTN  + (size_t)BB*HH*2)

// ---------------- helpers ----------------
__device__ __forceinline__ float sigm(float x){ return 1.f/(1.f+__expf(-x)); }

__device__ __forceinline__ float wred_sum(float v){
#pragma unroll
  for (int s=32; s>0; s>>=1) v += __shfl_xor(v, s, 64);
  return v;
}
__device__ __forceinline__ float wred_max(float v){
#pragma unroll
  for (int s=32; s>0; s>>=1) v = fmaxf(v, __shfl_xor(v, s, 64));
  return v;
}

// device-scope grid barrier (all NB blocks co-resident: 128 blocks <= 256 CUs)
__device__ __forceinline__ void gbar(unsigned* cnt, unsigned* gen){
  __syncthreads();
  if (threadIdx.x == 0) {
    unsigned g = __hip_atomic_load(gen, __ATOMIC_RELAXED, __HIP_MEMORY_SCOPE_AGENT);
    if (__hip_atomic_fetch_add(cnt, 1u, __ATOMIC_ACQ_REL, __HIP_MEMORY_SCOPE_AGENT) == (unsigned)(NB-1)) {
      __hip_atomic_store(cnt, 0u, __ATOMIC_RELAXED, __HIP_MEMORY_SCOPE_AGENT);
      __hip_atomic_fetch_add(gen, 1u, __ATOMIC_RELEASE, __HIP_MEMORY_SCOPE_AGENT);
    } else {
      unsigned long long spins = 0;
      while (__hip_atomic_load(gen, __ATOMIC_RELAXED, __HIP_MEMORY_SCOPE_AGENT) == g) {
        __builtin_amdgcn_s_sleep(1);
        if (++spins > (1ull<<22)) break;   // bail-out: fail loud, never hang
      }
      __builtin_amdgcn_fence(__ATOMIC_ACQUIRE, "agent");
    }
  }
  __syncthreads();
}

// ---------------- prologue kernels ----------------
// pack encoder weights: row p = bk*32 + jj*4 + gate  <-  orig gate*H + bk*8 + jj ; K = [Wih(256)|Whh(1024)]
__global__ void k_pack_enc(const float* __restrict__ wih, const float* __restrict__ whh,
                           __bf16* __restrict__ dst){
  int p = blockIdx.x;
  int gate = p & 3, jj = (p >> 2) & 7, bq = p >> 5;
  int orig = gate*HH + bq*8 + jj;
  const float* s0 = wih + (size_t)orig*DD;
  const float* s1 = whh + (size_t)orig*HH;
  __bf16* d = dst + (size_t)p*KENC;
  for (int k = threadIdx.x; k < KENC; k += blockDim.x)
    d[k] = (__bf16)(k < DD ? s0[k] : s1[k-DD]);
}
__global__ void k_pack_lstm(const float* __restrict__ wih, const float* __restrict__ whh,
                            __bf16* __restrict__ dst){
  int p = blockIdx.x;
  int gate = p & 3, jj = (p >> 2) & 7, bq = p >> 5;
  int orig = gate*HH + bq*8 + jj;
  const float* s0 = wih + (size_t)orig*HH;
  const float* s1 = whh + (size_t)orig*HH;
  __bf16* d = dst + (size_t)p*KLSTM;
  for (int k = threadIdx.x; k < KLSTM; k += blockDim.x)
    d[k] = (__bf16)(k < HH ? s0[k] : s1[k-HH]);
}
__global__ void k_conv(const float* __restrict__ src, __bf16* __restrict__ dst, int n){
  int i = blockIdx.x*blockDim.x + threadIdx.x;
  if (i < n) dst[i] = (__bf16)src[i];
}
// demo[0][b][l][d] -> demoB[l][b][d]
__global__ void k_conv_demo(const float* __restrict__ demo, __bf16* __restrict__ dst){
  int b = blockIdx.x & 63, l = blockIdx.x >> 6;
  int d = threadIdx.x;
  dst[((size_t)(l*BB + b))*DD + d] = (__bf16)demo[((size_t)(b*LL + l))*DD + d];
}

// ---------------- persistent main kernel ----------------
__global__ __launch_bounds__(NT)
void k_main(const int* __restrict__ demlen,
            const float* __restrict__ h0, const float* __restrict__ c0,
            const float* __restrict__ enc_bih, const float* __restrict__ enc_bhh,
            const float* __restrict__ attn_w, const float* __restrict__ attn_bias,
            const float* __restrict__ comb_b,
            const float* __restrict__ lstm_bih, const float* __restrict__ lstm_bhh,
            const float* __restrict__ mid_b,
            const float* __restrict__ out_w, const float* __restrict__ out_b,
            float* __restrict__ out, char* __restrict__ ws){
  const int bk = blockIdx.x, tid = threadIdx.x;
  const int wv = tid >> 6, ln = tid & 63;
  const int l15 = ln & 15, lhi = ln >> 4;
  const int klane = lhi * 8;

  __bf16* wEnc  = (__bf16*)(ws + OFF_WENC);
  __bf16* wLstm = (__bf16*)(ws + OFF_WLSTM);
  __bf16* wComb = (__bf16*)(ws + OFF_WCOMB);
  __bf16* wMid  = (__bf16*)(ws + OFF_WMID);
  __bf16* demoB = (__bf16*)(ws + OFF_DEMO);
  __bf16* stateB= (__bf16*)(ws + OFF_STATE);
  __bf16* encB  = (__bf16*)(ws + OFF_ENC);
  __bf16* hdec  = (__bf16*)(ws + OFF_HDEC);
  __bf16* mf    = (__bf16*)(ws + OFF_MF);
  float*  scored= (float*)(ws + OFF_SCORED);
  float*  hf    = (float*)(ws + OFF_HF);
  float*  cf    = (float*)(ws + OFF_CF);
  __bf16* hb0   = (__bf16*)(ws + OFF_HB0);
  __bf16* hb1   = (__bf16*)(ws + OFF_HB1);
  __bf16* xb    = (__bf16*)(ws + OFF_XB);
  __bf16* attnb = (__bf16*)(ws + OFF_ATTN);
  unsigned* cnt = (unsigned*)(ws + OFF_BAR);
  unsigned* gen = (unsigned*)(ws + OFF_BAR + 64);

  __shared__ float g_lds[BB*33];   // 64x32 gate tile, padded stride 33
  __shared__ float w_sh[LL];
  __shared__ float red_sh[4];

  const int gtid = bk*NT + tid;

  // wave -> tile assignment for the 64x32 (M x Nslice) GEMMs
  const int nt_ = wv & 1;          // n-tile (16 cols) within the 32-col slice
  const int mt0 = (wv >> 1) * 32;  // first of two 16-row m-tiles

  // ---- init: zero encoder h, c ----
  for (int i = gtid; i < BB*HH; i += NB*NT) { cf[i] = 0.f; hb0[i] = (__bf16)0.f; }
  gbar(cnt, gen);

  // ================= encoder: 80 LSTM steps =================
  for (int t = 0; t < LL; ++t) {
    const __bf16* hbR = (t & 1) ? hb1 : hb0;
    __bf16*       hbW = (t & 1) ? hb0 : hb1;
    const __bf16* A0 = demoB + (size_t)t*BB*DD;

    f32x4 acc0 = {0.f,0.f,0.f,0.f}, acc1 = {0.f,0.f,0.f,0.f};
    const __bf16* brow = wEnc + (size_t)(bk*32 + nt_*16 + l15)*KENC;
    const int am0 = mt0 + l15, am1 = am0 + 16;
#pragma unroll 4
    for (int kk = 0; kk < KENC; kk += 32) {
      int k0 = kk + klane;
      bf16x8 bfr = *(const bf16x8*)(brow + k0);
      const __bf16 *pa0, *pa1;
      if (k0 < DD) { pa0 = A0 + am0*DD + k0;        pa1 = A0 + am1*DD + k0; }
      else         { pa0 = hbR + am0*HH + (k0-DD);  pa1 = hbR + am1*HH + (k0-DD); }
      acc0 = __builtin_amdgcn_mfma_f32_16x16x32_bf16(*(const bf16x8*)pa0, bfr, acc0, 0,0,0);
      acc1 = __builtin_amdgcn_mfma_f32_16x16x32_bf16(*(const bf16x8*)pa1, bfr, acc1, 0,0,0);
    }
    {
      int col = nt_*16 + l15;
      int r0 = mt0 + lhi*4;
#pragma unroll
      for (int r = 0; r < 4; ++r) {
        g_lds[(r0+r)*33 + col]    = acc0[r];
        g_lds[(r0+16+r)*33 + col] = acc1[r];
      }
    }
    __syncthreads();
    for (int o = tid; o < BB*8; o += NT) {
      int m = o >> 3, jj = o & 7;
      int j = bk*8 + jj;
      float gi = g_lds[m*33 + jj*4+0] + enc_bih[j]      + enc_bhh[j];
      float gf = g_lds[m*33 + jj*4+1] + enc_bih[HH+j]   + enc_bhh[HH+j];
      float gg = g_lds[m*33 + jj*4+2] + enc_bih[2*HH+j] + enc_bhh[2*HH+j];
      float go = g_lds[m*33 + jj*4+3] + enc_bih[3*HH+j] + enc_bhh[3*HH+j];
      float cold = cf[m*HH + j];
      float cn = sigm(gf)*cold + sigm(gi)*tanhf(gg);
      float hn = sigm(go)*tanhf(cn);
      cf[m*HH + j] = cn;
      __bf16 hnb = (__bf16)hn;
      hbW[m*HH + j] = hnb;
      encB[((size_t)m*LL + t)*HH + j] = hnb;
    }
    gbar(cnt, gen);
  }

  // ================= score_d precompute + decoder h/c init =================
  {
    for (int d = 0; d < 10; ++d) {
      int idx = bk*40 + wv*10 + d;              // 0..5119 = b*80 + l
      int b = idx / LL, l = idx - b*LL;
      const __bf16* er = encB + ((size_t)b*LL + l)*HH;
      float part = 0.f;
#pragma unroll 4
      for (int k = ln; k < HH; k += 64) part += (float)er[k] * attn_w[k];
      part = wred_sum(part);
      if (ln == 0) scored[idx] = part + attn_bias[0];
    }
    for (int i = gtid; i < BB*HH; i += NB*NT) {
      float hv = h0[i];
      hf[i] = hv; cf[i] = c0[i]; hb0[i] = (__bf16)hv;
    }
  }
  gbar(cnt, gen);

  // ================= decoder: 40 steps x 3 phases =================
  for (int t = 0; t < TT; ++t) {
    const __bf16* hbR = (t & 1) ? hb1 : hb0;
    __bf16*       hbW = (t & 1) ? hb0 : hb1;

    // ---- phase A: scores -> softmax -> attn (block = (b, half of H)) ----
    {
      int b = bk >> 1, half = bk & 1;
      float sp = 0.f;
      for (int k = tid; k < HH; k += NT) sp += hf[b*HH + k] * attn_w[HH + k];
      sp = wred_sum(sp);
      if (ln == 0) red_sh[wv] = sp;
      __syncthreads();
      float s_b = red_sh[0] + red_sh[1] + red_sh[2] + red_sh[3];
      int len = demlen[b];
      if (wv == 0) {
        float sc0 = (ln < len) ? scored[b*LL + ln] + s_b : -1e30f;
        float sc1 = (ln < 16 && (64+ln) < len) ? scored[b*LL + 64 + ln] + s_b : -1e30f;
        float mx = wred_max(fmaxf(sc0, sc1));
        float e0 = __expf(sc0 - mx);
        float e1 = (ln < 16) ? __expf(sc1 - mx) : 0.f;
        float inv = 1.f / wred_sum(e0 + e1);
        w_sh[ln] = e0 * inv;
        if (ln < 16) w_sh[64+ln] = e1 * inv;
      }
      __syncthreads();
      const __bf16* eb = encB + (size_t)b*LL*HH + half*512;
      float a0 = 0.f, a1 = 0.f;
      for (int l = 0; l < LL; ++l) {
        float wl = w_sh[l];
        a0 += wl * (float)eb[(size_t)l*HH + tid];
        a1 += wl * (float)eb[(size_t)l*HH + 256 + tid];
      }
      attnb[b*HH + half*512 + tid]       = (__bf16)a0;
      attnb[b*HH + half*512 + 256 + tid] = (__bf16)a1;
    }
    gbar(cnt, gen);

    // ---- phase B: x = relu([attn|obs] @ combW^T + comb_b) (64 blocks) ----
    if (bk < BB) {
      f32x4 acc = {0.f,0.f,0.f,0.f};
      const __bf16* brow = wComb + (size_t)(bk*16 + l15)*KCOMB;
      const __bf16* A1 = stateB + (size_t)t*BB*DD;
      const int am = wv*16 + l15;
#pragma unroll 4
      for (int kk = 0; kk < KCOMB; kk += 32) {
        int k0 = kk + klane;
        bf16x8 bfr = *(const bf16x8*)(brow + k0);
        const __bf16* pa = (k0 < HH) ? (attnb + am*HH + k0) : (A1 + am*DD + (k0-HH));
        acc = __builtin_amdgcn_mfma_f32_16x16x32_bf16(*(const bf16x8*)pa, bfr, acc, 0,0,0);
      }
      int col = bk*16 + l15;
      float cb = comb_b[col];
      int r0 = wv*16 + lhi*4;
#pragma unroll
      for (int r = 0; r < 4; ++r) {
        float v = fmaxf(acc[r] + cb, 0.f);
        xb[(r0+r)*HH + col] = (__bf16)v;
      }
    }
    gbar(cnt, gen);

    // ---- phase C: LSTM cell ----
    {
      f32x4 acc0 = {0.f,0.f,0.f,0.f}, acc1 = {0.f,0.f,0.f,0.f};
      const __bf16* brow = wLstm + (size_t)(bk*32 + nt_*16 + l15)*KLSTM;
      const int am0 = mt0 + l15, am1 = am0 + 16;
#pragma unroll 4
      for (int kk = 0; kk < KLSTM; kk += 32) {
        int k0 = kk + klane;
        bf16x8 bfr = *(const bf16x8*)(brow + k0);
        const __bf16 *pa0, *pa1;
        if (k0 < HH) { pa0 = xb  + am0*HH + k0;       pa1 = xb  + am1*HH + k0; }
        else         { pa0 = hbR + am0*HH + (k0-HH);  pa1 = hbR + am1*HH + (k0-HH); }
        acc0 = __builtin_amdgcn_mfma_f32_16x16x32_bf16(*(const bf16x8*)pa0, bfr, acc0, 0,0,0);
        acc1 = __builtin_amdgcn_mfma_f32_16x16x32_bf16(*(const bf16x8*)pa1, bfr, acc1, 0,0,0);
      }
      {
        int col = nt_*16 + l15;
        int r0 = mt0 + lhi*4;
#pragma unroll
        for (int r = 0; r < 4; ++r) {
          g_lds[(r0+r)*33 + col]    = acc0[r];
          g_lds[(r0+16+r)*33 + col] = acc1[r];
        }
      }
      __syncthreads();
      for (int o = tid; o < BB*8; o += NT) {
        int m = o >> 3, jj = o & 7;
        int j = bk*8 + jj;
        float gi = g_lds[m*33 + jj*4+0] + lstm_bih[j]      + lstm_bhh[j];
        float gf = g_lds[m*33 + jj*4+1] + lstm_bih[HH+j]   + lstm_bhh[HH+j];
        float gg = g_lds[m*33 + jj*4+2] + lstm_bih[2*HH+j] + lstm_bhh[2*HH+j];
        float go = g_lds[m*33 + jj*4+3] + lstm_bih[3*HH+j] + lstm_bhh[3*HH+j];
        float cold = cf[m*HH + j];
        float cn = sigm(gf)*cold + sigm(gi)*tanhf(gg);
        float hn = sigm(go)*tanhf(cn);
        cf[m*HH + j] = cn; hf[m*HH + j] = hn;
        __bf16 hnb = (__bf16)hn;
        hbW[m*HH + j] = hnb;
        hdec[((size_t)t*BB + m)*HH + j] = hnb;
      }
    }
    gbar(cnt, gen);
  }

  // ================= epilogue: m = hdec @ midW^T + mid_b (2560x1024x1024) =================
  {
    int gid = bk*4 + wv;
    for (int i = 0; i < 20; ++i) {
      int ti = i*512 + gid;
      int mt = ti >> 6, nt2 = ti & 63;
      f32x4 acc = {0.f,0.f,0.f,0.f};
      const __bf16* brow = wMid + (size_t)(nt2*16 + l15)*HH;
      const __bf16* arow = hdec + (size_t)(mt*16 + l15)*HH;
#pragma unroll 4
      for (int kk = 0; kk < HH; kk += 32) {
        int k0 = kk + klane;
        acc = __builtin_amdgcn_mfma_f32_16x16x32_bf16(*(const bf16x8*)(arow + k0),
                                                      *(const bf16x8*)(brow + k0), acc, 0,0,0);
      }
      int col = nt2*16 + l15;
      float mb = mid_b[col];
      int r0 = mt*16 + lhi*4;
#pragma unroll
      for (int r = 0; r < 4; ++r)
        mf[(size_t)(r0+r)*HH + col] = (__bf16)(acc[r] + mb);
    }
  }
  gbar(cnt, gen);

  // ================= q = mf @ outW^T + out_b ; copy final h,c =================
  {
    for (int i = 0; i < 5; ++i) {
      int row = bk*20 + wv*5 + i;
      const __bf16* mr = mf + (size_t)row*HH;
      float mreg[16];
#pragma unroll
      for (int k = 0; k < 16; ++k) mreg[k] = (float)mr[ln + 64*k];
      for (int a = 0; a < AA; ++a) {
        float p = 0.f;
#pragma unroll
        for (int k = 0; k < 16; ++k) p += mreg[k] * out_w[a*HH + ln + 64*k];
        p = wred_sum(p);
        if (ln == 0) out[(size_t)row*AA + a] = p + out_b[a];
      }
    }
    for (int i = gtid; i < BB*HH; i += NB*NT) {
      out[QSZ + i]         = hf[i];
      out[QSZ + BB*HH + i] = cf[i];
    }
  }
}

// ---------------- host launch ----------------
extern "C" void kernel_launch(void* const* d_in, const int* in_sizes, int n_in,
                              void* d_out, int out_size, void* d_ws, size_t ws_size,
                              hipStream_t stream) {
  (void)in_sizes; (void)n_in; (void)out_size; (void)ws_size;
  const float* state    = (const float*)d_in[0];
  const float* demo     = (const float*)d_in[1];
  const int*   demlen   = (const int*)d_in[2];
  const float* h0       = (const float*)d_in[3];
  const float* c0       = (const float*)d_in[4];
  const float* enc_wih  = (const float*)d_in[5];
  const float* enc_whh  = (const float*)d_in[6];
  const float* enc_bih  = (const float*)d_in[7];
  const float* enc_bhh  = (const float*)d_in[8];
  const float* attn_w   = (const float*)d_in[9];
  const float* attn_b   = (const float*)d_in[10];
  const float* comb_w   = (const float*)d_in[11];
  const float* comb_b   = (const float*)d_in[12];
  const float* lstm_wih = (const float*)d_in[13];
  const float* lstm_whh = (const float*)d_in[14];
  const float* lstm_bih = (const float*)d_in[15];
  const float* lstm_bhh = (const float*)d_in[16];
  const float* mid_w    = (const float*)d_in[17];
  const float* mid_b    = (const float*)d_in[18];
  const float* out_w    = (const float*)d_in[19];
  const float* out_b    = (const float*)d_in[20];
  char* ws = (char*)d_ws;

  hipMemsetAsync(ws + OFF_BAR, 0, 256, stream);
  k_pack_enc <<<G4H, 256, 0, stream>>>(enc_wih, enc_whh, (__bf16*)(ws + OFF_WENC));
  k_pack_lstm<<<G4H, 256, 0, stream>>>(lstm_wih, lstm_whh, (__bf16*)(ws + OFF_WLSTM));
  k_conv<<<(HH*KCOMB + 255)/256, 256, 0, stream>>>(comb_w, (__bf16*)(ws + OFF_WCOMB), HH*KCOMB);
  k_conv<<<(HH*HH   + 255)/256, 256, 0, stream>>>(mid_w,  (__bf16*)(ws + OFF_WMID),  HH*HH);
  k_conv_demo<<<LL*BB, DD, 0, stream>>>(demo, (__bf16*)(ws + OFF_DEMO));
  k_conv<<<(TT*BB*DD + 255)/256, 256, 0, stream>>>(state, (__bf16*)(ws + OFF_STATE), TT*BB*DD);
  k_main<<<NB, NT, 0, stream>>>(demlen, h0, c0, enc_bih, enc_bhh, attn_w, attn_b,
                                comb_b, lstm_bih, lstm_bhh, mid_b, out_w, out_b,
                                (float*)d_out, ws);
}

// Round 3
// 3703.595 us; speedup vs baseline: 1.4283x; 1.4283x over previous
//
#include <hip/hip_runtime.h>
#include <hip/hip_bf16.h>

// ---------------- problem dims ----------------
#define TT 40
#define BB 64
#define LL 80
#define DD 256
#define HH 1024
#define G4H 4096
#define AA 18
#define KENC 1280   // [demo(256) | h(1024)]
#define KLSTM 2048  // [x(1024) | h(1024)]
#define KCOMB 1280  // [attn(1024) | obs(256)]
#define NB 128
#define NT 256
#define QSZ (TT*BB*AA)

typedef __bf16 bf16x8 __attribute__((ext_vector_type(8)));
typedef float  f32x4  __attribute__((ext_vector_type(4)));

// ---------------- workspace layout (bytes) ----------------
// All cross-block state is either (a) written with sc0sc1 write-through stores
// and read at never-before-touched addresses (compulsory miss -> LLC), or
// (b) block-private (cf). No acquire invalidations anywhere -> weights stay
// L1/L2-resident across all 125 barriers.
#define OFF_WENC   ((size_t)0)
#define OFF_WLSTM  (OFF_WENC  + (size_t)G4H*KENC*2)
#define OFF_WCOMB  (OFF_WLSTM + (size_t)G4H*KLSTM*2)
#define OFF_WMID   (OFF_WCOMB + (size_t)HH*KCOMB*2)
#define OFF_BIASE  (OFF_WMID  + (size_t)HH*HH*2)
#define OFF_BIASL  (OFF_BIASE + (size_t)G4H*4)
#define OFF_DEMO   (OFF_BIASL + (size_t)G4H*4)
#define OFF_STATE  (OFF_DEMO  + (size_t)BB*LL*DD*2)
#define OFF_ENC    (OFF_STATE + (size_t)TT*BB*DD*2)
#define OFF_HDEC   (OFF_ENC   + (size_t)BB*LL*HH*2)
#define OFF_XALL   (OFF_HDEC  + (size_t)TT*BB*HH*2)
#define OFF_MF     (OFF_XALL  + (size_t)TT*BB*HH*2)
#define OFF_ATTNS  (OFF_MF    + (size_t)TT*BB*HH*2)
#define OFF_CF     (OFF_ATTNS + (size_t)BB*HH*2)
#define OFF_HROT   (OFF_CF    + (size_t)BB*HH*4)
#define NSLOT_E    81
#define NSLOT_D    41
#define OFF_BAR    (OFF_HROT  + (size_t)(NSLOT_E+NSLOT_D)*BB*HH*2)

// ---------------- helpers ----------------
__device__ __forceinline__ float sigm(float x){ return 1.f/(1.f+__expf(-x)); }

__device__ __forceinline__ float wred_sum(float v){
#pragma unroll
  for (int s=32; s>0; s>>=1) v += __shfl_xor(v, s, 64);
  return v;
}
__device__ __forceinline__ float wred_max(float v){
#pragma unroll
  for (int s=32; s>0; s>>=1) v = fmaxf(v, __shfl_xor(v, s, 64));
  return v;
}

__device__ __forceinline__ unsigned pack_bf16(float a, float b){
  unsigned short ua = __builtin_bit_cast(unsigned short, (__bf16)a);
  unsigned short ub = __builtin_bit_cast(unsigned short, (__bf16)b);
  return (unsigned)ua | ((unsigned)ub << 16);
}
__device__ __forceinline__ float bfl(unsigned v){
  return (float)__builtin_bit_cast(__bf16, (unsigned short)(v & 0xffffu));
}
__device__ __forceinline__ float bfh(unsigned v){
  return (float)__builtin_bit_cast(__bf16, (unsigned short)(v >> 16));
}

// write-through (coherent) stores: visible at LLC, no L2 write-allocate
__device__ __forceinline__ void st_u32_sc(unsigned* p, unsigned v){
  __hip_atomic_store(p, v, __ATOMIC_RELAXED, __HIP_MEMORY_SCOPE_AGENT);
}
__device__ __forceinline__ void st_b16_sc(__bf16* p, float v){
  unsigned short u = __builtin_bit_cast(unsigned short, (__bf16)v);
  asm volatile("global_store_short %0, %1, off sc0 sc1"
               :: "v"(p), "v"((unsigned)u) : "memory");
}

// monotonic grid barrier: no acquire fence (no cache invalidation).
// target = number of barriers completed including this one.
__device__ __forceinline__ void gbar(unsigned* cnt, unsigned* gen, unsigned target){
  __syncthreads();   // compiler emits waitcnt -> all this wave's stores drained
  if (threadIdx.x == 0) {
    __builtin_amdgcn_fence(__ATOMIC_RELEASE, "agent");   // writeback-only; cheap (almost nothing dirty)
    unsigned old = __hip_atomic_fetch_add(cnt, 1u, __ATOMIC_RELAXED, __HIP_MEMORY_SCOPE_AGENT);
    (void)old;
    if (old == target*(unsigned)NB - 1u) {
      __hip_atomic_fetch_add(gen, 1u, __ATOMIC_RELAXED, __HIP_MEMORY_SCOPE_AGENT);
    } else {
      unsigned long long spins = 0;
      while (__hip_atomic_load(gen, __ATOMIC_RELAXED, __HIP_MEMORY_SCOPE_AGENT) < target) {
        __builtin_amdgcn_s_sleep(2);
        if (++spins > (1ull<<22)) break;   // fail loud, never hang
      }
    }
  }
  __syncthreads();
  asm volatile("" ::: "memory");
}

// ---------------- prologue kernels ----------------
// packed gate row p = blk*32 + jj*4 + gate  <->  orig row gate*H + blk*8 + jj
__global__ void k_pack_enc(const float* __restrict__ wih, const float* __restrict__ whh,
                           const float* __restrict__ bih, const float* __restrict__ bhh,
                           __bf16* __restrict__ dst, float* __restrict__ bias){
  int p = blockIdx.x;
  int gate = p & 3, jj = (p >> 2) & 7, bq = p >> 5;
  int orig = gate*HH + bq*8 + jj;
  if (threadIdx.x == 0) bias[p] = bih[orig] + bhh[orig];
  const float* s0 = wih + (size_t)orig*DD;
  const float* s1 = whh + (size_t)orig*HH;
  __bf16* d = dst + (size_t)p*KENC;
  for (int k = threadIdx.x; k < KENC; k += blockDim.x)
    d[k] = (__bf16)(k < DD ? s0[k] : s1[k-DD]);
}
__global__ void k_pack_lstm(const float* __restrict__ wih, const float* __restrict__ whh,
                            const float* __restrict__ bih, const float* __restrict__ bhh,
                            __bf16* __restrict__ dst, float* __restrict__ bias){
  int p = blockIdx.x;
  int gate = p & 3, jj = (p >> 2) & 7, bq = p >> 5;
  int orig = gate*HH + bq*8 + jj;
  if (threadIdx.x == 0) bias[p] = bih[orig] + bhh[orig];
  const float* s0 = wih + (size_t)orig*HH;
  const float* s1 = whh + (size_t)orig*HH;
  __bf16* d = dst + (size_t)p*KLSTM;
  for (int k = threadIdx.x; k < KLSTM; k += blockDim.x)
    d[k] = (__bf16)(k < HH ? s0[k] : s1[k-HH]);
}
__global__ void k_conv(const float* __restrict__ src, __bf16* __restrict__ dst, int n){
  int i = blockIdx.x*blockDim.x + threadIdx.x;
  if (i < n) dst[i] = (__bf16)src[i];
}

// ---------------- persistent main kernel ----------------
__global__ __launch_bounds__(NT)
void k_main(const int* __restrict__ demlen,
            const float* __restrict__ h0, const float* __restrict__ c0,
            const float* __restrict__ attn_w, const float* __restrict__ attn_bias,
            const float* __restrict__ comb_b, const float* __restrict__ mid_b,
            const float* __restrict__ out_w, const float* __restrict__ out_b,
            float* __restrict__ out, char* __restrict__ ws){
  const int bk = blockIdx.x, tid = threadIdx.x;
  const int wv = tid >> 6, ln = tid & 63;
  const int l15 = ln & 15, lhi = ln >> 4;
  const int klane = lhi * 8;
  const int gtid = bk*NT + tid;

  __bf16* wEnc  = (__bf16*)(ws + OFF_WENC);
  __bf16* wLstm = (__bf16*)(ws + OFF_WLSTM);
  __bf16* wComb = (__bf16*)(ws + OFF_WCOMB);
  __bf16* wMid  = (__bf16*)(ws + OFF_WMID);
  const float* bE = (const float*)(ws + OFF_BIASE);
  const float* bL = (const float*)(ws + OFF_BIASL);
  __bf16* demoC = (__bf16*)(ws + OFF_DEMO);
  __bf16* stateB= (__bf16*)(ws + OFF_STATE);
  __bf16* encB  = (__bf16*)(ws + OFF_ENC);
  __bf16* hdec  = (__bf16*)(ws + OFF_HDEC);
  __bf16* xall  = (__bf16*)(ws + OFF_XALL);
  __bf16* mf    = (__bf16*)(ws + OFF_MF);
  __bf16* attnS = (__bf16*)(ws + OFF_ATTNS);
  float*  cf    = (float*)(ws + OFF_CF);
  __bf16* hrotE = (__bf16*)(ws + OFF_HROT);
  __bf16* hrotD = hrotE + (size_t)NSLOT_E*BB*HH;
  unsigned* cnt = (unsigned*)(ws + OFF_BAR);
  unsigned* gen = (unsigned*)(ws + OFF_BAR + 64);

  __shared__ float g_lds[BB*33];   // 64x32 gate tile, stride 33 (pad)
  __shared__ float sc_sh[LL];
  __shared__ float w_sh[LL];

  unsigned bar = 0;
  const int m_ = tid >> 2, p_ = tid & 3;     // elementwise item: batch row, jj-pair
  const int j0_ = bk*8 + 2*p_;               // this block's h columns

  // ---- init: zero h slot 0 (sc) + private cf ----
  for (int i = gtid; i < BB*HH/2; i += NB*NT) st_u32_sc((unsigned*)hrotE + i, 0u);
  cf[m_*HH + j0_] = 0.f; cf[m_*HH + j0_ + 1] = 0.f;
  gbar(cnt, gen, ++bar);

  // ================= encoder: 80 LSTM steps, 1 barrier each =================
  for (int t = 0; t < LL; ++t) {
    const __bf16* hR = hrotE + (size_t)t*BB*HH;
    __bf16*       hW = hrotE + (size_t)(t+1)*BB*HH;

    f32x4 acc0 = {0.f,0.f,0.f,0.f}, acc1 = {0.f,0.f,0.f,0.f};
    const __bf16* b0 = wEnc + (size_t)(bk*32 + l15)*KENC;
    const __bf16* b1 = b0 + (size_t)16*KENC;
    const int am = wv*16 + l15;
#pragma unroll 8
    for (int kk = 0; kk < KENC; kk += 32) {
      int k0 = kk + klane;
      bf16x8 af = (k0 < DD) ? *(const bf16x8*)(demoC + ((size_t)am*LL + t)*DD + k0)
                            : *(const bf16x8*)(hR + (size_t)am*HH + (k0-DD));
      acc0 = __builtin_amdgcn_mfma_f32_16x16x32_bf16(af, *(const bf16x8*)(b0 + k0), acc0, 0,0,0);
      acc1 = __builtin_amdgcn_mfma_f32_16x16x32_bf16(af, *(const bf16x8*)(b1 + k0), acc1, 0,0,0);
    }
    {
      int r0 = wv*16 + lhi*4;
#pragma unroll
      for (int r = 0; r < 4; ++r) {
        g_lds[(r0+r)*33 + l15]      = acc0[r];
        g_lds[(r0+r)*33 + 16 + l15] = acc1[r];
      }
    }
    __syncthreads();
    {
      int base = m_*33 + p_*8, cb = bk*32 + p_*8;
      float gi0 = g_lds[base+0]+bE[cb+0], gf0 = g_lds[base+1]+bE[cb+1];
      float gg0 = g_lds[base+2]+bE[cb+2], go0 = g_lds[base+3]+bE[cb+3];
      float gi1 = g_lds[base+4]+bE[cb+4], gf1 = g_lds[base+5]+bE[cb+5];
      float gg1 = g_lds[base+6]+bE[cb+6], go1 = g_lds[base+7]+bE[cb+7];
      float cA = cf[m_*HH + j0_], cB = cf[m_*HH + j0_ + 1];
      float cn0 = sigm(gf0)*cA + sigm(gi0)*tanhf(gg0);
      float cn1 = sigm(gf1)*cB + sigm(gi1)*tanhf(gg1);
      float hn0 = sigm(go0)*tanhf(cn0);
      float hn1 = sigm(go1)*tanhf(cn1);
      cf[m_*HH + j0_] = cn0; cf[m_*HH + j0_ + 1] = cn1;
      unsigned hp = pack_bf16(hn0, hn1);
      st_u32_sc((unsigned*)(hW + (size_t)m_*HH + j0_), hp);
      st_u32_sc((unsigned*)(encB + ((size_t)m_*LL + t)*HH + j0_), hp);
    }
    gbar(cnt, gen, ++bar);
  }

  // ================= phase S: static attention (softmax is h-independent:
  //   scores = score_d[b,l] + (h.Wh)[b] -> per-row constant shift cancels) ====
  {
    int b = bk >> 1, half = bk & 1;
    // 80 score dots (per block, duplicated x2 across halves; trivial FLOPs)
    for (int i = 0; i < 20; ++i) {
      int l = wv*20 + i;
      const __bf16* er = encB + ((size_t)b*LL + l)*HH + ln*16;
      bf16x8 e0 = *(const bf16x8*)(er);
      bf16x8 e1 = *(const bf16x8*)(er + 8);
      float part = 0.f;
#pragma unroll
      for (int j = 0; j < 8; ++j) {
        part += (float)e0[j] * attn_w[ln*16 + j];
        part += (float)e1[j] * attn_w[ln*16 + 8 + j];
      }
      part = wred_sum(part);
      if (ln == 0) sc_sh[l] = part;
    }
    __syncthreads();
    if (wv == 0) {
      int len = demlen[b];
      float s0 = (ln < len) ? sc_sh[ln] : -1e30f;
      float s1 = (ln < 16 && 64+ln < len) ? sc_sh[64+ln] : -1e30f;
      float mx = wred_max(fmaxf(s0, s1));
      float e0 = __expf(s0 - mx);
      float e1 = (ln < 16) ? __expf(s1 - mx) : 0.f;
      float inv = 1.f / wred_sum(e0 + e1);
      w_sh[ln] = e0 * inv;
      if (ln < 16) w_sh[64+ln] = e1 * inv;
    }
    __syncthreads();
    int cc0 = half*512 + 2*tid;
    float a0 = 0.f, a1 = 0.f;
    const __bf16* eb = encB + (size_t)b*LL*HH;
#pragma unroll 4
    for (int l = 0; l < LL; ++l) {
      unsigned v = *(const unsigned*)(eb + (size_t)l*HH + cc0);
      float wl = w_sh[l];
      a0 += wl * bfl(v); a1 += wl * bfh(v);
    }
    st_u32_sc((unsigned*)(attnS + (size_t)b*HH + cc0), pack_bf16(a0, a1));
    // decoder state init: h0 -> dslot0 (sc), c0 -> private cf
    for (int i = gtid; i < BB*HH/2; i += NB*NT) {
      int i2 = i*2;
      st_u32_sc((unsigned*)hrotD + i, pack_bf16(h0[i2], h0[i2+1]));
    }
    cf[m_*HH + j0_]     = c0[m_*HH + j0_];
    cf[m_*HH + j0_ + 1] = c0[m_*HH + j0_ + 1];
  }
  gbar(cnt, gen, ++bar);

  // ================= phase X: x_all = relu([attn|obs_t]@combW^T + b), all t ==
  {
    int wgid = bk*4 + wv;
    for (int i = 0; i < 10; ++i) {
      int ti = i*512 + wgid;          // 0..5119
      int mt = ti >> 5, np = ti & 31; // 160 m-tiles x 32 n-pairs
      f32x4 acc0 = {0.f,0.f,0.f,0.f}, acc1 = {0.f,0.f,0.f,0.f};
      const __bf16* b0 = wComb + (size_t)(np*32 + l15)*KCOMB;
      const __bf16* b1 = b0 + (size_t)16*KCOMB;
      int r = mt*16 + l15, bb = r & 63;
#pragma unroll 8
      for (int kk = 0; kk < KCOMB; kk += 32) {
        int k0 = kk + klane;
        bf16x8 af = (k0 < HH) ? *(const bf16x8*)(attnS + (size_t)bb*HH + k0)
                              : *(const bf16x8*)(stateB + (size_t)r*DD + (k0-HH));
        acc0 = __builtin_amdgcn_mfma_f32_16x16x32_bf16(af, *(const bf16x8*)(b0 + k0), acc0, 0,0,0);
        acc1 = __builtin_amdgcn_mfma_f32_16x16x32_bf16(af, *(const bf16x8*)(b1 + k0), acc1, 0,0,0);
      }
      int col = np*32 + l15;
      float cb0 = comb_b[col], cb1 = comb_b[col+16];
      int r0 = mt*16 + lhi*4;
#pragma unroll
      for (int rr = 0; rr < 4; ++rr) {
        st_b16_sc(xall + (size_t)(r0+rr)*HH + col,      fmaxf(acc0[rr]+cb0, 0.f));
        st_b16_sc(xall + (size_t)(r0+rr)*HH + col + 16, fmaxf(acc1[rr]+cb1, 0.f));
      }
    }
  }
  gbar(cnt, gen, ++bar);

  // ================= decoder: 40 steps, ONE barrier each =================
  for (int t = 0; t < TT; ++t) {
    const __bf16* hR = hrotD + (size_t)t*BB*HH;
    __bf16*       hW = hrotD + (size_t)(t+1)*BB*HH;
    const __bf16* xA = xall + (size_t)t*BB*HH;

    f32x4 acc0 = {0.f,0.f,0.f,0.f}, acc1 = {0.f,0.f,0.f,0.f};
    const __bf16* b0 = wLstm + (size_t)(bk*32 + l15)*KLSTM;
    const __bf16* b1 = b0 + (size_t)16*KLSTM;
    const int am = wv*16 + l15;
#pragma unroll 8
    for (int kk = 0; kk < KLSTM; kk += 32) {
      int k0 = kk + klane;
      bf16x8 af = (k0 < HH) ? *(const bf16x8*)(xA + (size_t)am*HH + k0)
                            : *(const bf16x8*)(hR + (size_t)am*HH + (k0-HH));
      acc0 = __builtin_amdgcn_mfma_f32_16x16x32_bf16(af, *(const bf16x8*)(b0 + k0), acc0, 0,0,0);
      acc1 = __builtin_amdgcn_mfma_f32_16x16x32_bf16(af, *(const bf16x8*)(b1 + k0), acc1, 0,0,0);
    }
    {
      int r0 = wv*16 + lhi*4;
#pragma unroll
      for (int r = 0; r < 4; ++r) {
        g_lds[(r0+r)*33 + l15]      = acc0[r];
        g_lds[(r0+r)*33 + 16 + l15] = acc1[r];
      }
    }
    __syncthreads();
    {
      int base = m_*33 + p_*8, cb = bk*32 + p_*8;
      float gi0 = g_lds[base+0]+bL[cb+0], gf0 = g_lds[base+1]+bL[cb+1];
      float gg0 = g_lds[base+2]+bL[cb+2], go0 = g_lds[base+3]+bL[cb+3];
      float gi1 = g_lds[base+4]+bL[cb+4], gf1 = g_lds[base+5]+bL[cb+5];
      float gg1 = g_lds[base+6]+bL[cb+6], go1 = g_lds[base+7]+bL[cb+7];
      float cA = cf[m_*HH + j0_], cB = cf[m_*HH + j0_ + 1];
      float cn0 = sigm(gf0)*cA + sigm(gi0)*tanhf(gg0);
      float cn1 = sigm(gf1)*cB + sigm(gi1)*tanhf(gg1);
      float hn0 = sigm(go0)*tanhf(cn0);
      float hn1 = sigm(go1)*tanhf(cn1);
      cf[m_*HH + j0_] = cn0; cf[m_*HH + j0_ + 1] = cn1;
      unsigned hp = pack_bf16(hn0, hn1);
      st_u32_sc((unsigned*)(hW + (size_t)m_*HH + j0_), hp);
      st_u32_sc((unsigned*)(hdec + ((size_t)t*BB + m_)*HH + j0_), hp);
      if (t == TT-1) {  // exact fp32 final h straight from registers
        out[QSZ + m_*HH + j0_]     = hn0;
        out[QSZ + m_*HH + j0_ + 1] = hn1;
      }
    }
    gbar(cnt, gen, ++bar);
  }

  // final c (block-private columns, exact fp32)
  out[QSZ + BB*HH + m_*HH + j0_]     = cf[m_*HH + j0_];
  out[QSZ + BB*HH + m_*HH + j0_ + 1] = cf[m_*HH + j0_ + 1];

  // ================= epilogue: m = hdec @ midW^T + mid_b =================
  {
    int wgid = bk*4 + wv;
    for (int i = 0; i < 10; ++i) {
      int ti = i*512 + wgid;
      int mt = ti >> 5, np = ti & 31;
      f32x4 acc0 = {0.f,0.f,0.f,0.f}, acc1 = {0.f,0.f,0.f,0.f};
      const __bf16* b0 = wMid + (size_t)(np*32 + l15)*HH;
      const __bf16* b1 = b0 + (size_t)16*HH;
      const __bf16* ar = hdec + (size_t)(mt*16 + l15)*HH;
#pragma unroll 8
      for (int kk = 0; kk < HH; kk += 32) {
        int k0 = kk + klane;
        bf16x8 af = *(const bf16x8*)(ar + k0);
        acc0 = __builtin_amdgcn_mfma_f32_16x16x32_bf16(af, *(const bf16x8*)(b0 + k0), acc0, 0,0,0);
        acc1 = __builtin_amdgcn_mfma_f32_16x16x32_bf16(af, *(const bf16x8*)(b1 + k0), acc1, 0,0,0);
      }
      int col = np*32 + l15;
      float mb0 = mid_b[col], mb1 = mid_b[col+16];
      int r0 = mt*16 + lhi*4;
#pragma unroll
      for (int rr = 0; rr < 4; ++rr) {
        st_b16_sc(mf + (size_t)(r0+rr)*HH + col,      acc0[rr]+mb0);
        st_b16_sc(mf + (size_t)(r0+rr)*HH + col + 16, acc1[rr]+mb1);
      }
    }
  }
  gbar(cnt, gen, ++bar);

  // ================= q = mf @ outW^T + out_b =================
  {
    for (int i = 0; i < 5; ++i) {
      int row = (bk*4 + wv)*5 + i;
      const __bf16* mr = mf + (size_t)row*HH;
      float mreg[16];
#pragma unroll
      for (int k = 0; k < 16; ++k) mreg[k] = (float)mr[ln + 64*k];
      for (int a = 0; a < AA; ++a) {
        float p = 0.f;
#pragma unroll
        for (int k = 0; k < 16; ++k) p += mreg[k] * out_w[(size_t)a*HH + ln + 64*k];
        p = wred_sum(p);
        if (ln == 0) out[(size_t)row*AA + a] = p + out_b[a];
      }
    }
  }
}

// ---------------- host launch ----------------
extern "C" void kernel_launch(void* const* d_in, const int* in_sizes, int n_in,
                              void* d_out, int out_size, void* d_ws, size_t ws_size,
                              hipStream_t stream) {
  (void)in_sizes; (void)n_in; (void)out_size; (void)ws_size;
  const float* state    = (const float*)d_in[0];
  const float* demo     = (const float*)d_in[1];
  const int*   demlen   = (const int*)d_in[2];
  const float* h0       = (const float*)d_in[3];
  const float* c0       = (const float*)d_in[4];
  const float* enc_wih  = (const float*)d_in[5];
  const float* enc_whh  = (const float*)d_in[6];
  const float* enc_bih  = (const float*)d_in[7];
  const float* enc_bhh  = (const float*)d_in[8];
  const float* attn_w   = (const float*)d_in[9];
  const float* attn_b   = (const float*)d_in[10];
  const float* comb_w   = (const float*)d_in[11];
  const float* comb_b   = (const float*)d_in[12];
  const float* lstm_wih = (const float*)d_in[13];
  const float* lstm_whh = (const float*)d_in[14];
  const float* lstm_bih = (const float*)d_in[15];
  const float* lstm_bhh = (const float*)d_in[16];
  const float* mid_w    = (const float*)d_in[17];
  const float* mid_b    = (const float*)d_in[18];
  const float* out_w    = (const float*)d_in[19];
  const float* out_b    = (const float*)d_in[20];
  char* ws = (char*)d_ws;

  (void)hipMemsetAsync(ws + OFF_BAR, 0, 256, stream);
  k_pack_enc <<<G4H, 256, 0, stream>>>(enc_wih, enc_whh, enc_bih, enc_bhh,
                                       (__bf16*)(ws + OFF_WENC), (float*)(ws + OFF_BIASE));
  k_pack_lstm<<<G4H, 256, 0, stream>>>(lstm_wih, lstm_whh, lstm_bih, lstm_bhh,
                                       (__bf16*)(ws + OFF_WLSTM), (float*)(ws + OFF_BIASL));
  k_conv<<<(HH*KCOMB + 255)/256, 256, 0, stream>>>(comb_w, (__bf16*)(ws + OFF_WCOMB), HH*KCOMB);
  k_conv<<<(HH*HH   + 255)/256, 256, 0, stream>>>(mid_w,  (__bf16*)(ws + OFF_WMID),  HH*HH);
  k_conv<<<(BB*LL*DD + 255)/256, 256, 0, stream>>>(demo,  (__bf16*)(ws + OFF_DEMO),  BB*LL*DD);
  k_conv<<<(TT*BB*DD + 255)/256, 256, 0, stream>>>(state, (__bf16*)(ws + OFF_STATE), TT*BB*DD);
  k_main<<<NB, NT, 0, stream>>>(demlen, h0, c0, attn_w, attn_b, comb_b, mid_b,
                                out_w, out_b, (float*)d_out, ws);
}

// Round 4
// 3440.010 us; speedup vs baseline: 1.5378x; 1.0766x over previous
//
#include <hip/hip_runtime.h>
#include <hip/hip_bf16.h>

// ---------------- problem dims ----------------
#define TT 40
#define BB 64
#define LL 80
#define DD 256
#define HH 1024
#define G4H 4096
#define AA 18
#define KENC 1280   // [demo(256) | h(1024)]
#define KLSTM 2048  // [x(1024) | h(1024)]
#define KCOMB 1280  // [attn(1024) | obs(256)]
#define NB 128
#define NT 256
#define QSZ (TT*BB*AA)

typedef __bf16 bf16x8 __attribute__((ext_vector_type(8)));
typedef float  f32x4  __attribute__((ext_vector_type(4)));

// ---------------- workspace layout (bytes) ----------------
#define OFF_WENC   ((size_t)0)
#define OFF_WLSTM  (OFF_WENC  + (size_t)G4H*KENC*2)
#define OFF_WCOMB  (OFF_WLSTM + (size_t)G4H*KLSTM*2)
#define OFF_WMID   (OFF_WCOMB + (size_t)HH*KCOMB*2)
#define OFF_BIASE  (OFF_WMID  + (size_t)HH*HH*2)
#define OFF_BIASL  (OFF_BIASE + (size_t)G4H*4)
#define OFF_DEMO   (OFF_BIASL + (size_t)G4H*4)
#define OFF_STATE  (OFF_DEMO  + (size_t)BB*LL*DD*2)
#define OFF_ENC    (OFF_STATE + (size_t)TT*BB*DD*2)
#define OFF_HDEC   (OFF_ENC   + (size_t)BB*LL*HH*2)
#define OFF_XALL   (OFF_HDEC  + (size_t)TT*BB*HH*2)
#define OFF_MF     (OFF_XALL  + (size_t)TT*BB*HH*2)
#define OFF_ATTNS  (OFF_MF    + (size_t)TT*BB*HH*2)
#define OFF_CF     (OFF_ATTNS + (size_t)BB*HH*2)
#define OFF_HROT   (OFF_CF    + (size_t)BB*HH*4)
#define NSLOT_E    81
#define NSLOT_D    41
#define OFF_BAR    (OFF_HROT  + (size_t)(NSLOT_E+NSLOT_D)*BB*HH*2)
#define FLAG_STRIDE 16          // dwords: 64B per flag -> no same-line contention
#define BAR_BYTES  (NB*FLAG_STRIDE*4)

// ---------------- helpers ----------------
__device__ __forceinline__ float sigm(float x){ return 1.f/(1.f+__expf(-x)); }

__device__ __forceinline__ float wred_sum(float v){
#pragma unroll
  for (int s=32; s>0; s>>=1) v += __shfl_xor(v, s, 64);
  return v;
}
__device__ __forceinline__ float wred_max(float v){
#pragma unroll
  for (int s=32; s>0; s>>=1) v = fmaxf(v, __shfl_xor(v, s, 64));
  return v;
}

__device__ __forceinline__ unsigned pack_bf16(float a, float b){
  unsigned short ua = __builtin_bit_cast(unsigned short, (__bf16)a);
  unsigned short ub = __builtin_bit_cast(unsigned short, (__bf16)b);
  return (unsigned)ua | ((unsigned)ub << 16);
}
__device__ __forceinline__ float bfl(unsigned v){
  return (float)__builtin_bit_cast(__bf16, (unsigned short)(v & 0xffffu));
}
__device__ __forceinline__ float bfh(unsigned v){
  return (float)__builtin_bit_cast(__bf16, (unsigned short)(v >> 16));
}

// write-through (coherent) stores: visible at LLC, no L2 write-allocate
__device__ __forceinline__ void st_u32_sc(unsigned* p, unsigned v){
  __hip_atomic_store(p, v, __ATOMIC_RELAXED, __HIP_MEMORY_SCOPE_AGENT);
}
__device__ __forceinline__ void st_b16_sc(__bf16* p, float v){
  unsigned short u = __builtin_bit_cast(unsigned short, (__bf16)v);
  asm volatile("global_store_short %0, %1, off sc0 sc1"
               :: "v"(p), "v"((unsigned)u) : "memory");
}

// all-to-all flag barrier: zero same-address atomic contention.
// Each block stores its arrival epoch to its own 64B-spaced flag; wave 0 of
// every block polls all NB flags (2 lane-strided agent loads) until
// min(flags) >= target. Monotonic epochs make overtaking safe.
__device__ __forceinline__ void gbar(unsigned* flags, unsigned target, int bk){
  __syncthreads();   // compiler drains vmcnt before s_barrier -> stores done
  const int tid = threadIdx.x;
  if (tid == 0) {
    __builtin_amdgcn_fence(__ATOMIC_RELEASE, "agent");  // writeback, no invalidate
    __hip_atomic_store(flags + (size_t)bk*FLAG_STRIDE, target,
                       __ATOMIC_RELAXED, __HIP_MEMORY_SCOPE_AGENT);
  }
  if (tid < 64) {
    unsigned long long spins = 0;
    for (;;) {
      unsigned a = __hip_atomic_load(flags + (size_t)tid*FLAG_STRIDE,
                                     __ATOMIC_RELAXED, __HIP_MEMORY_SCOPE_AGENT);
      unsigned b = __hip_atomic_load(flags + (size_t)(64+tid)*FLAG_STRIDE,
                                     __ATOMIC_RELAXED, __HIP_MEMORY_SCOPE_AGENT);
      if (__all((int)(a >= target && b >= target))) break;
      if (++spins > (1ull<<20)) break;   // fail loud, never hang
      __builtin_amdgcn_s_sleep(1);
    }
  }
  __syncthreads();
  asm volatile("" ::: "memory");
}

// ---------------- prologue kernels ----------------
// packed gate row p = blk*32 + jj*4 + gate  <->  orig row gate*H + blk*8 + jj
__global__ void k_pack_enc(const float* __restrict__ wih, const float* __restrict__ whh,
                           const float* __restrict__ bih, const float* __restrict__ bhh,
                           __bf16* __restrict__ dst, float* __restrict__ bias){
  int p = blockIdx.x;
  int gate = p & 3, jj = (p >> 2) & 7, bq = p >> 5;
  int orig = gate*HH + bq*8 + jj;
  if (threadIdx.x == 0) bias[p] = bih[orig] + bhh[orig];
  const float* s0 = wih + (size_t)orig*DD;
  const float* s1 = whh + (size_t)orig*HH;
  __bf16* d = dst + (size_t)p*KENC;
  for (int k = threadIdx.x; k < KENC; k += blockDim.x)
    d[k] = (__bf16)(k < DD ? s0[k] : s1[k-DD]);
}
__global__ void k_pack_lstm(const float* __restrict__ wih, const float* __restrict__ whh,
                            const float* __restrict__ bih, const float* __restrict__ bhh,
                            __bf16* __restrict__ dst, float* __restrict__ bias){
  int p = blockIdx.x;
  int gate = p & 3, jj = (p >> 2) & 7, bq = p >> 5;
  int orig = gate*HH + bq*8 + jj;
  if (threadIdx.x == 0) bias[p] = bih[orig] + bhh[orig];
  const float* s0 = wih + (size_t)orig*HH;
  const float* s1 = whh + (size_t)orig*HH;
  __bf16* d = dst + (size_t)p*KLSTM;
  for (int k = threadIdx.x; k < KLSTM; k += blockDim.x)
    d[k] = (__bf16)(k < HH ? s0[k] : s1[k-HH]);
}
__global__ void k_conv(const float* __restrict__ src, __bf16* __restrict__ dst, int n){
  int i = blockIdx.x*blockDim.x + threadIdx.x;
  if (i < n) dst[i] = (__bf16)src[i];
}

// ---------------- persistent main kernel ----------------
__global__ __launch_bounds__(NT)
void k_main(const int* __restrict__ demlen,
            const float* __restrict__ h0, const float* __restrict__ c0,
            const float* __restrict__ attn_w, const float* __restrict__ attn_bias,
            const float* __restrict__ comb_b, const float* __restrict__ mid_b,
            const float* __restrict__ out_w, const float* __restrict__ out_b,
            float* __restrict__ out, char* __restrict__ ws){
  const int bk = blockIdx.x, tid = threadIdx.x;
  const int wv = tid >> 6, ln = tid & 63;
  const int l15 = ln & 15, lhi = ln >> 4;
  const int klane = lhi * 8;
  const int gtid = bk*NT + tid;

  __bf16* wEnc  = (__bf16*)(ws + OFF_WENC);
  __bf16* wLstm = (__bf16*)(ws + OFF_WLSTM);
  __bf16* wComb = (__bf16*)(ws + OFF_WCOMB);
  __bf16* wMid  = (__bf16*)(ws + OFF_WMID);
  const float* bE = (const float*)(ws + OFF_BIASE);
  const float* bL = (const float*)(ws + OFF_BIASL);
  __bf16* demoC = (__bf16*)(ws + OFF_DEMO);
  __bf16* stateB= (__bf16*)(ws + OFF_STATE);
  __bf16* encB  = (__bf16*)(ws + OFF_ENC);
  __bf16* hdec  = (__bf16*)(ws + OFF_HDEC);
  __bf16* xall  = (__bf16*)(ws + OFF_XALL);
  __bf16* mf    = (__bf16*)(ws + OFF_MF);
  __bf16* attnS = (__bf16*)(ws + OFF_ATTNS);
  float*  cf    = (float*)(ws + OFF_CF);
  __bf16* hrotE = (__bf16*)(ws + OFF_HROT);
  __bf16* hrotD = hrotE + (size_t)NSLOT_E*BB*HH;
  unsigned* flags = (unsigned*)(ws + OFF_BAR);

  __shared__ float g_lds[BB*33];   // 64x32 gate tile, stride 33 (pad)
  __shared__ float sc_sh[LL];
  __shared__ float w_sh[LL];

  unsigned bar = 0;
  const int m_ = tid >> 2, p_ = tid & 3;     // elementwise item: batch row, jj-pair
  const int j0_ = bk*8 + 2*p_;               // this block's h columns

  // ---- init: zero h slot 0 (sc) + private cf ----
  for (int i = gtid; i < BB*HH/2; i += NB*NT) st_u32_sc((unsigned*)hrotE + i, 0u);
  cf[m_*HH + j0_] = 0.f; cf[m_*HH + j0_ + 1] = 0.f;
  gbar(flags, ++bar, bk);

  // ================= encoder: 80 LSTM steps, 1 barrier each =================
  for (int t = 0; t < LL; ++t) {
    const __bf16* hR = hrotE + (size_t)t*BB*HH;
    __bf16*       hW = hrotE + (size_t)(t+1)*BB*HH;

    f32x4 acc0 = {0.f,0.f,0.f,0.f}, acc1 = {0.f,0.f,0.f,0.f};
    const __bf16* b0 = wEnc + (size_t)(bk*32 + l15)*KENC;
    const __bf16* b1 = b0 + (size_t)16*KENC;
    const int am = wv*16 + l15;
#pragma unroll 8
    for (int kk = 0; kk < KENC; kk += 32) {
      int k0 = kk + klane;
      bf16x8 af = (k0 < DD) ? *(const bf16x8*)(demoC + ((size_t)am*LL + t)*DD + k0)
                            : *(const bf16x8*)(hR + (size_t)am*HH + (k0-DD));
      acc0 = __builtin_amdgcn_mfma_f32_16x16x32_bf16(af, *(const bf16x8*)(b0 + k0), acc0, 0,0,0);
      acc1 = __builtin_amdgcn_mfma_f32_16x16x32_bf16(af, *(const bf16x8*)(b1 + k0), acc1, 0,0,0);
    }
    {
      int r0 = wv*16 + lhi*4;
#pragma unroll
      for (int r = 0; r < 4; ++r) {
        g_lds[(r0+r)*33 + l15]      = acc0[r];
        g_lds[(r0+r)*33 + 16 + l15] = acc1[r];
      }
    }
    __syncthreads();
    {
      int base = m_*33 + p_*8, cb = bk*32 + p_*8;
      float gi0 = g_lds[base+0]+bE[cb+0], gf0 = g_lds[base+1]+bE[cb+1];
      float gg0 = g_lds[base+2]+bE[cb+2], go0 = g_lds[base+3]+bE[cb+3];
      float gi1 = g_lds[base+4]+bE[cb+4], gf1 = g_lds[base+5]+bE[cb+5];
      float gg1 = g_lds[base+6]+bE[cb+6], go1 = g_lds[base+7]+bE[cb+7];
      float cA = cf[m_*HH + j0_], cB = cf[m_*HH + j0_ + 1];
      float cn0 = sigm(gf0)*cA + sigm(gi0)*tanhf(gg0);
      float cn1 = sigm(gf1)*cB + sigm(gi1)*tanhf(gg1);
      float hn0 = sigm(go0)*tanhf(cn0);
      float hn1 = sigm(go1)*tanhf(cn1);
      cf[m_*HH + j0_] = cn0; cf[m_*HH + j0_ + 1] = cn1;
      unsigned hp = pack_bf16(hn0, hn1);
      st_u32_sc((unsigned*)(hW + (size_t)m_*HH + j0_), hp);
      st_u32_sc((unsigned*)(encB + ((size_t)m_*LL + t)*HH + j0_), hp);
    }
    gbar(flags, ++bar, bk);
  }

  // ================= phase S: static attention (softmax is h-independent:
  //   scores = score_d[b,l] + (h.Wh)[b] -> per-row constant shift cancels) ====
  {
    int b = bk >> 1, half = bk & 1;
    for (int i = 0; i < 20; ++i) {
      int l = wv*20 + i;
      const __bf16* er = encB + ((size_t)b*LL + l)*HH + ln*16;
      bf16x8 e0 = *(const bf16x8*)(er);
      bf16x8 e1 = *(const bf16x8*)(er + 8);
      float part = 0.f;
#pragma unroll
      for (int j = 0; j < 8; ++j) {
        part += (float)e0[j] * attn_w[ln*16 + j];
        part += (float)e1[j] * attn_w[ln*16 + 8 + j];
      }
      part = wred_sum(part);
      if (ln == 0) sc_sh[l] = part;
    }
    __syncthreads();
    if (wv == 0) {
      int len = demlen[b];
      float s0 = (ln < len) ? sc_sh[ln] : -1e30f;
      float s1 = (ln < 16 && 64+ln < len) ? sc_sh[64+ln] : -1e30f;
      float mx = wred_max(fmaxf(s0, s1));
      float e0 = __expf(s0 - mx);
      float e1 = (ln < 16) ? __expf(s1 - mx) : 0.f;
      float inv = 1.f / wred_sum(e0 + e1);
      w_sh[ln] = e0 * inv;
      if (ln < 16) w_sh[64+ln] = e1 * inv;
    }
    __syncthreads();
    int cc0 = half*512 + 2*tid;
    float a0 = 0.f, a1 = 0.f;
    const __bf16* eb = encB + (size_t)b*LL*HH;
#pragma unroll 4
    for (int l = 0; l < LL; ++l) {
      unsigned v = *(const unsigned*)(eb + (size_t)l*HH + cc0);
      float wl = w_sh[l];
      a0 += wl * bfl(v); a1 += wl * bfh(v);
    }
    st_u32_sc((unsigned*)(attnS + (size_t)b*HH + cc0), pack_bf16(a0, a1));
    // decoder state init: h0 -> dslot0 (sc), c0 -> private cf
    for (int i = gtid; i < BB*HH/2; i += NB*NT) {
      int i2 = i*2;
      st_u32_sc((unsigned*)hrotD + i, pack_bf16(h0[i2], h0[i2+1]));
    }
    cf[m_*HH + j0_]     = c0[m_*HH + j0_];
    cf[m_*HH + j0_ + 1] = c0[m_*HH + j0_ + 1];
  }
  gbar(flags, ++bar, bk);

  // ================= phase X: x_all = relu([attn|obs_t]@combW^T + b), all t ==
  {
    int wgid = bk*4 + wv;
    for (int i = 0; i < 10; ++i) {
      int ti = i*512 + wgid;          // 0..5119
      int mt = ti >> 5, np = ti & 31; // 160 m-tiles x 32 n-pairs
      f32x4 acc0 = {0.f,0.f,0.f,0.f}, acc1 = {0.f,0.f,0.f,0.f};
      const __bf16* b0 = wComb + (size_t)(np*32 + l15)*KCOMB;
      const __bf16* b1 = b0 + (size_t)16*KCOMB;
      int r = mt*16 + l15, bb = r & 63;
#pragma unroll 8
      for (int kk = 0; kk < KCOMB; kk += 32) {
        int k0 = kk + klane;
        bf16x8 af = (k0 < HH) ? *(const bf16x8*)(attnS + (size_t)bb*HH + k0)
                              : *(const bf16x8*)(stateB + (size_t)r*DD + (k0-HH));
        acc0 = __builtin_amdgcn_mfma_f32_16x16x32_bf16(af, *(const bf16x8*)(b0 + k0), acc0, 0,0,0);
        acc1 = __builtin_amdgcn_mfma_f32_16x16x32_bf16(af, *(const bf16x8*)(b1 + k0), acc1, 0,0,0);
      }
      int col = np*32 + l15;
      float cb0 = comb_b[col], cb1 = comb_b[col+16];
      int r0 = mt*16 + lhi*4;
#pragma unroll
      for (int rr = 0; rr < 4; ++rr) {
        st_b16_sc(xall + (size_t)(r0+rr)*HH + col,      fmaxf(acc0[rr]+cb0, 0.f));
        st_b16_sc(xall + (size_t)(r0+rr)*HH + col + 16, fmaxf(acc1[rr]+cb1, 0.f));
      }
    }
  }
  gbar(flags, ++bar, bk);

  // ================= decoder: 40 steps, ONE barrier each =================
  for (int t = 0; t < TT; ++t) {
    const __bf16* hR = hrotD + (size_t)t*BB*HH;
    __bf16*       hW = hrotD + (size_t)(t+1)*BB*HH;
    const __bf16* xA = xall + (size_t)t*BB*HH;

    f32x4 acc0 = {0.f,0.f,0.f,0.f}, acc1 = {0.f,0.f,0.f,0.f};
    const __bf16* b0 = wLstm + (size_t)(bk*32 + l15)*KLSTM;
    const __bf16* b1 = b0 + (size_t)16*KLSTM;
    const int am = wv*16 + l15;
#pragma unroll 8
    for (int kk = 0; kk < KLSTM; kk += 32) {
      int k0 = kk + klane;
      bf16x8 af = (k0 < HH) ? *(const bf16x8*)(xA + (size_t)am*HH + k0)
                            : *(const bf16x8*)(hR + (size_t)am*HH + (k0-HH));
      acc0 = __builtin_amdgcn_mfma_f32_16x16x32_bf16(af, *(const bf16x8*)(b0 + k0), acc0, 0,0,0);
      acc1 = __builtin_amdgcn_mfma_f32_16x16x32_bf16(af, *(const bf16x8*)(b1 + k0), acc1, 0,0,0);
    }
    {
      int r0 = wv*16 + lhi*4;
#pragma unroll
      for (int r = 0; r < 4; ++r) {
        g_lds[(r0+r)*33 + l15]      = acc0[r];
        g_lds[(r0+r)*33 + 16 + l15] = acc1[r];
      }
    }
    __syncthreads();
    {
      int base = m_*33 + p_*8, cb = bk*32 + p_*8;
      float gi0 = g_lds[base+0]+bL[cb+0], gf0 = g_lds[base+1]+bL[cb+1];
      float gg0 = g_lds[base+2]+bL[cb+2], go0 = g_lds[base+3]+bL[cb+3];
      float gi1 = g_lds[base+4]+bL[cb+4], gf1 = g_lds[base+5]+bL[cb+5];
      float gg1 = g_lds[base+6]+bL[cb+6], go1 = g_lds[base+7]+bL[cb+7];
      float cA = cf[m_*HH + j0_], cB = cf[m_*HH + j0_ + 1];
      float cn0 = sigm(gf0)*cA + sigm(gi0)*tanhf(gg0);
      float cn1 = sigm(gf1)*cB + sigm(gi1)*tanhf(gg1);
      float hn0 = sigm(go0)*tanhf(cn0);
      float hn1 = sigm(go1)*tanhf(cn1);
      cf[m_*HH + j0_] = cn0; cf[m_*HH + j0_ + 1] = cn1;
      unsigned hp = pack_bf16(hn0, hn1);
      st_u32_sc((unsigned*)(hW + (size_t)m_*HH + j0_), hp);
      st_u32_sc((unsigned*)(hdec + ((size_t)t*BB + m_)*HH + j0_), hp);
      if (t == TT-1) {  // exact fp32 final h straight from registers
        out[QSZ + m_*HH + j0_]     = hn0;
        out[QSZ + m_*HH + j0_ + 1] = hn1;
      }
    }
    gbar(flags, ++bar, bk);
  }

  // final c (block-private columns, exact fp32)
  out[QSZ + BB*HH + m_*HH + j0_]     = cf[m_*HH + j0_];
  out[QSZ + BB*HH + m_*HH + j0_ + 1] = cf[m_*HH + j0_ + 1];

  // ================= epilogue: m = hdec @ midW^T + mid_b =================
  {
    int wgid = bk*4 + wv;
    for (int i = 0; i < 10; ++i) {
      int ti = i*512 + wgid;
      int mt = ti >> 5, np = ti & 31;
      f32x4 acc0 = {0.f,0.f,0.f,0.f}, acc1 = {0.f,0.f,0.f,0.f};
      const __bf16* b0 = wMid + (size_t)(np*32 + l15)*HH;
      const __bf16* b1 = b0 + (size_t)16*HH;
      const __bf16* ar = hdec + (size_t)(mt*16 + l15)*HH;
#pragma unroll 8
      for (int kk = 0; kk < HH; kk += 32) {
        int k0 = kk + klane;
        bf16x8 af = *(const bf16x8*)(ar + k0);
        acc0 = __builtin_amdgcn_mfma_f32_16x16x32_bf16(af, *(const bf16x8*)(b0 + k0), acc0, 0,0,0);
        acc1 = __builtin_amdgcn_mfma_f32_16x16x32_bf16(af, *(const bf16x8*)(b1 + k0), acc1, 0,0,0);
      }
      int col = np*32 + l15;
      float mb0 = mid_b[col], mb1 = mid_b[col+16];
      int r0 = mt*16 + lhi*4;
#pragma unroll
      for (int rr = 0; rr < 4; ++rr) {
        st_b16_sc(mf + (size_t)(r0+rr)*HH + col,      acc0[rr]+mb0);
        st_b16_sc(mf + (size_t)(r0+rr)*HH + col + 16, acc1[rr]+mb1);
      }
    }
  }
  gbar(flags, ++bar, bk);

  // ================= q = mf @ outW^T + out_b =================
  {
    for (int i = 0; i < 5; ++i) {
      int row = (bk*4 + wv)*5 + i;
      const __bf16* mr = mf + (size_t)row*HH;
      float mreg[16];
#pragma unroll
      for (int k = 0; k < 16; ++k) mreg[k] = (float)mr[ln + 64*k];
      for (int a = 0; a < AA; ++a) {
        float p = 0.f;
#pragma unroll
        for (int k = 0; k < 16; ++k) p += mreg[k] * out_w[(size_t)a*HH + ln + 64*k];
        p = wred_sum(p);
        if (ln == 0) out[(size_t)row*AA + a] = p + out_b[a];
      }
    }
  }
}

// ---------------- host launch ----------------
extern "C" void kernel_launch(void* const* d_in, const int* in_sizes, int n_in,
                              void* d_out, int out_size, void* d_ws, size_t ws_size,
                              hipStream_t stream) {
  (void)in_sizes; (void)n_in; (void)out_size; (void)ws_size;
  const float* state    = (const float*)d_in[0];
  const float* demo     = (const float*)d_in[1];
  const int*   demlen   = (const int*)d_in[2];
  const float* h0       = (const float*)d_in[3];
  const float* c0       = (const float*)d_in[4];
  const float* enc_wih  = (const float*)d_in[5];
  const float* enc_whh  = (const float*)d_in[6];
  const float* enc_bih  = (const float*)d_in[7];
  const float* enc_bhh  = (const float*)d_in[8];
  const float* attn_w   = (const float*)d_in[9];
  const float* attn_b   = (const float*)d_in[10];
  const float* comb_w   = (const float*)d_in[11];
  const float* comb_b   = (const float*)d_in[12];
  const float* lstm_wih = (const float*)d_in[13];
  const float* lstm_whh = (const float*)d_in[14];
  const float* lstm_bih = (const float*)d_in[15];
  const float* lstm_bhh = (const float*)d_in[16];
  const float* mid_w    = (const float*)d_in[17];
  const float* mid_b    = (const float*)d_in[18];
  const float* out_w    = (const float*)d_in[19];
  const float* out_b    = (const float*)d_in[20];
  char* ws = (char*)d_ws;

  (void)hipMemsetAsync(ws + OFF_BAR, 0, BAR_BYTES, stream);
  k_pack_enc <<<G4H, 256, 0, stream>>>(enc_wih, enc_whh, enc_bih, enc_bhh,
                                       (__bf16*)(ws + OFF_WENC), (float*)(ws + OFF_BIASE));
  k_pack_lstm<<<G4H, 256, 0, stream>>>(lstm_wih, lstm_whh, lstm_bih, lstm_bhh,
                                       (__bf16*)(ws + OFF_WLSTM), (float*)(ws + OFF_BIASL));
  k_conv<<<(HH*KCOMB + 255)/256, 256, 0, stream>>>(comb_w, (__bf16*)(ws + OFF_WCOMB), HH*KCOMB);
  k_conv<<<(HH*HH   + 255)/256, 256, 0, stream>>>(mid_w,  (__bf16*)(ws + OFF_WMID),  HH*HH);
  k_conv<<<(BB*LL*DD + 255)/256, 256, 0, stream>>>(demo,  (__bf16*)(ws + OFF_DEMO),  BB*LL*DD);
  k_conv<<<(TT*BB*DD + 255)/256, 256, 0, stream>>>(state, (__bf16*)(ws + OFF_STATE), TT*BB*DD);
  k_main<<<NB, NT, 0, stream>>>(demlen, h0, c0, attn_w, attn_b, comb_b, mid_b,
                                out_w, out_b, (float*)d_out, ws);
}

// Round 5
// 2435.992 us; speedup vs baseline: 2.1716x; 1.4122x over previous
//
#include <hip/hip_runtime.h>
#include <hip/hip_bf16.h>

// ---------------- problem dims ----------------
#define TT 40
#define BB 64
#define LL 80
#define DD 256
#define HH 1024
#define G4H 4096
#define AA 18
#define KENC 1280   // [demo(256) | h(1024)]
#define KLSTM 2048  // [x(1024) | h(1024)]
#define KCOMB 1280  // [attn(1024) | obs(256)]
#define NB 256
#define NT 256
#define QSZ (TT*BB*AA)

typedef __bf16 bf16x8 __attribute__((ext_vector_type(8)));
typedef float  f32x4  __attribute__((ext_vector_type(4)));

// ---------------- workspace layout (bytes) ----------------
#define OFF_WENC   ((size_t)0)
#define OFF_WLSTM  (OFF_WENC  + (size_t)G4H*KENC*2)
#define OFF_WCOMB  (OFF_WLSTM + (size_t)G4H*KLSTM*2)
#define OFF_WMID   (OFF_WCOMB + (size_t)HH*KCOMB*2)
#define OFF_BIASE  (OFF_WMID  + (size_t)HH*HH*2)
#define OFF_BIASL  (OFF_BIASE + (size_t)G4H*4)
#define OFF_DEMO   (OFF_BIASL + (size_t)G4H*4)
#define OFF_STATE  (OFF_DEMO  + (size_t)BB*LL*DD*2)
#define OFF_ENC    (OFF_STATE + (size_t)TT*BB*DD*2)
#define OFF_HDEC   (OFF_ENC   + (size_t)BB*LL*HH*2)
#define OFF_XALL   (OFF_HDEC  + (size_t)TT*BB*HH*2)
#define OFF_MF     (OFF_XALL  + (size_t)TT*BB*HH*2)
#define OFF_ATTNS  (OFF_MF    + (size_t)TT*BB*HH*2)
#define OFF_CF     (OFF_ATTNS + (size_t)BB*HH*2)
#define OFF_HROT   (OFF_CF    + (size_t)BB*HH*4)
#define NSLOT_E    81
#define NSLOT_D    41
#define OFF_BAR    (OFF_HROT  + (size_t)(NSLOT_E+NSLOT_D)*BB*HH*2)
#define FLAG_STRIDE 16          // dwords: 64B per flag
#define BAR_BYTES  (NB*FLAG_STRIDE*4)

// ---------------- helpers ----------------
__device__ __forceinline__ float sigm(float x){ return 1.f/(1.f+__expf(-x)); }

__device__ __forceinline__ float wred_sum(float v){
#pragma unroll
  for (int s=32; s>0; s>>=1) v += __shfl_xor(v, s, 64);
  return v;
}
__device__ __forceinline__ float wred_max(float v){
#pragma unroll
  for (int s=32; s>0; s>>=1) v = fmaxf(v, __shfl_xor(v, s, 64));
  return v;
}

__device__ __forceinline__ unsigned pack_bf16(float a, float b){
  unsigned short ua = __builtin_bit_cast(unsigned short, (__bf16)a);
  unsigned short ub = __builtin_bit_cast(unsigned short, (__bf16)b);
  return (unsigned)ua | ((unsigned)ub << 16);
}

// write-through (coherent) stores: visible at LLC, no stale L2 write-allocate
__device__ __forceinline__ void st_u32_sc(unsigned* p, unsigned v){
  __hip_atomic_store(p, v, __ATOMIC_RELAXED, __HIP_MEMORY_SCOPE_AGENT);
}
__device__ __forceinline__ void st_b16_sc(__bf16* p, float v){
  unsigned short u = __builtin_bit_cast(unsigned short, (__bf16)v);
  asm volatile("global_store_short %0, %1, off sc0 sc1"
               :: "v"(p), "v"((unsigned)u) : "memory");
}
// swizzled h store: element (m,j) at byte (m*2048+j*2)^((m&7)<<4)
__device__ __forceinline__ void st_h_swz(char* slot, int m, int j, float v){
  int byte = (m*2048 + j*2) ^ ((m & 7) << 4);
  st_b16_sc((__bf16*)(slot + byte), v);
}

// all-to-all flag barrier: zero same-address contention (R4 design, NB=256)
__device__ __forceinline__ void gbar(unsigned* flags, unsigned target, int bk){
  __syncthreads();
  const int tid = threadIdx.x;
  if (tid == 0) {
    __builtin_amdgcn_fence(__ATOMIC_RELEASE, "agent");  // writeback, no invalidate
    __hip_atomic_store(flags + (size_t)bk*FLAG_STRIDE, target,
                       __ATOMIC_RELAXED, __HIP_MEMORY_SCOPE_AGENT);
  }
  if (tid < 64) {
    unsigned long long spins = 0;
    for (;;) {
      unsigned a0 = __hip_atomic_load(flags + (size_t)tid*FLAG_STRIDE,        __ATOMIC_RELAXED, __HIP_MEMORY_SCOPE_AGENT);
      unsigned a1 = __hip_atomic_load(flags + (size_t)(64+tid)*FLAG_STRIDE,   __ATOMIC_RELAXED, __HIP_MEMORY_SCOPE_AGENT);
      unsigned a2 = __hip_atomic_load(flags + (size_t)(128+tid)*FLAG_STRIDE,  __ATOMIC_RELAXED, __HIP_MEMORY_SCOPE_AGENT);
      unsigned a3 = __hip_atomic_load(flags + (size_t)(192+tid)*FLAG_STRIDE,  __ATOMIC_RELAXED, __HIP_MEMORY_SCOPE_AGENT);
      bool ok = (a0 >= target) && (a1 >= target) && (a2 >= target) && (a3 >= target);
      if (__all((int)ok)) break;
      if (++spins > (1ull<<20)) break;   // fail loud, never hang
      __builtin_amdgcn_s_sleep(1);
    }
  }
  __syncthreads();
  asm volatile("" ::: "memory");
}

// ---------------- prologue kernels ----------------
// packed gate row p = blk*16 + jj*4 + gate  <->  orig row gate*H + blk*4 + jj
__global__ void k_pack_enc(const float* __restrict__ wih, const float* __restrict__ whh,
                           const float* __restrict__ bih, const float* __restrict__ bhh,
                           __bf16* __restrict__ dst, float* __restrict__ bias){
  int p = blockIdx.x;
  int gate = p & 3, jj = (p >> 2) & 3, bq = p >> 4;
  int orig = gate*HH + bq*4 + jj;
  if (threadIdx.x == 0) bias[p] = bih[orig] + bhh[orig];
  const float* s0 = wih + (size_t)orig*DD;
  const float* s1 = whh + (size_t)orig*HH;
  __bf16* d = dst + (size_t)p*KENC;
  for (int k = threadIdx.x; k < KENC; k += blockDim.x)
    d[k] = (__bf16)(k < DD ? s0[k] : s1[k-DD]);
}
__global__ void k_pack_lstm(const float* __restrict__ wih, const float* __restrict__ whh,
                            const float* __restrict__ bih, const float* __restrict__ bhh,
                            __bf16* __restrict__ dst, float* __restrict__ bias){
  int p = blockIdx.x;
  int gate = p & 3, jj = (p >> 2) & 3, bq = p >> 4;
  int orig = gate*HH + bq*4 + jj;
  if (threadIdx.x == 0) bias[p] = bih[orig] + bhh[orig];
  const float* s0 = wih + (size_t)orig*HH;
  const float* s1 = whh + (size_t)orig*HH;
  __bf16* d = dst + (size_t)p*KLSTM;
  for (int k = threadIdx.x; k < KLSTM; k += blockDim.x)
    d[k] = (__bf16)(k < HH ? s0[k] : s1[k-HH]);
}
__global__ void k_conv(const float* __restrict__ src, __bf16* __restrict__ dst, int n){
  int i = blockIdx.x*blockDim.x + threadIdx.x;
  if (i < n) dst[i] = (__bf16)src[i];
}

// ---------------- persistent main kernel ----------------
__global__ __launch_bounds__(NT, 1)
void k_main(const int* __restrict__ demlen,
            const float* __restrict__ h0, const float* __restrict__ c0,
            const float* __restrict__ attn_w,
            const float* __restrict__ comb_b, const float* __restrict__ mid_b,
            const float* __restrict__ out_w, const float* __restrict__ out_b,
            float* __restrict__ out, char* __restrict__ ws){
  const int bk = blockIdx.x, tid = threadIdx.x;
  const int wv = tid >> 6, ln = tid & 63;
  const int l15 = ln & 15, lhi = ln >> 4;
  const int klane = lhi * 8;
  const int gtid = bk*NT + tid;

  __bf16* wEnc  = (__bf16*)(ws + OFF_WENC);
  __bf16* wLstm = (__bf16*)(ws + OFF_WLSTM);
  __bf16* wComb = (__bf16*)(ws + OFF_WCOMB);
  __bf16* wMid  = (__bf16*)(ws + OFF_WMID);
  const float* bE = (const float*)(ws + OFF_BIASE);
  const float* bL = (const float*)(ws + OFF_BIASL);
  __bf16* demoC = (__bf16*)(ws + OFF_DEMO);
  __bf16* stateB= (__bf16*)(ws + OFF_STATE);
  __bf16* encB  = (__bf16*)(ws + OFF_ENC);
  __bf16* hdec  = (__bf16*)(ws + OFF_HDEC);
  __bf16* xall  = (__bf16*)(ws + OFF_XALL);
  __bf16* mf    = (__bf16*)(ws + OFF_MF);
  __bf16* attnS = (__bf16*)(ws + OFF_ATTNS);
  float*  cf    = (float*)(ws + OFF_CF);
  __bf16* hrotE = (__bf16*)(ws + OFF_HROT);
  __bf16* hrotD = hrotE + (size_t)NSLOT_E*BB*HH;
  unsigned* flags = (unsigned*)(ws + OFF_BAR);

  // LDS: staged h (swizzled content, 128 KB) + gate transpose tile + softmax
  __shared__ __align__(16) char lds_h[BB*HH*2];
  __shared__ float g_lds[BB*17];
  __shared__ float sc_sh[LL];
  __shared__ float w_sh[LL];

  unsigned bar = 0;
  const int m_ = tid >> 2, q_ = tid & 3;   // elementwise: batch row, jj
  const int jh = bk*4 + q_;                // this block's h column
  const int ar = wv*16 + l15;              // this lane's A row (batch)

  // ---- init: zero enc h slot 0, zero private cf cols ----
  for (int i = gtid; i < BB*HH/2; i += NB*NT) st_u32_sc((unsigned*)hrotE + i, 0u);
  cf[m_*HH + jh] = 0.f;
  gbar(flags, ++bar, bk);

  // ================= encoder: 80 steps =================
  for (int t = 0; t < LL; ++t) {
    const __bf16* hRg = hrotE + (size_t)t*BB*HH;
    char*         hWg = (char*)(hrotE + (size_t)(t+1)*BB*HH);

    // stage h -> LDS (linear copy; content pre-swizzled), 8-deep pipelined
    {
      const bf16x8* gs = (const bf16x8*)hRg;
      bf16x8* ls = (bf16x8*)lds_h;
#pragma unroll
      for (int rnd = 0; rnd < 4; ++rnd) {
        bf16x8 tmp[8];
#pragma unroll
        for (int u = 0; u < 8; ++u) tmp[u] = gs[(rnd*8+u)*NT + tid];
#pragma unroll
        for (int u = 0; u < 8; ++u) ls[(rnd*8+u)*NT + tid] = tmp[u];
      }
    }

    f32x4 acc = {0.f,0.f,0.f,0.f};
    const __bf16* brow = wEnc + (size_t)(bk*16 + l15)*KENC;
    const __bf16* arow = demoC + ((size_t)ar*LL + t)*DD;
    // demo part (global, overlaps staging latency)
#pragma unroll
    for (int kk = 0; kk < DD; kk += 32) {
      int k0 = kk + klane;
      acc = __builtin_amdgcn_mfma_f32_16x16x32_bf16(*(const bf16x8*)(arow + k0),
                                                    *(const bf16x8*)(brow + k0), acc, 0,0,0);
    }
    __syncthreads();   // staging complete
    // h part (A from LDS swizzled, B from L2)
#pragma unroll 8
    for (int kk = 0; kk < HH; kk += 32) {
      int k0 = kk + klane;
      int off = (ar*2048 + k0*2) ^ ((ar & 7) << 4);
      acc = __builtin_amdgcn_mfma_f32_16x16x32_bf16(*(const bf16x8*)(lds_h + off),
                                                    *(const bf16x8*)(brow + DD + k0), acc, 0,0,0);
    }
    // gate transpose via LDS
    {
      int r0 = wv*16 + lhi*4;
#pragma unroll
      for (int r = 0; r < 4; ++r) g_lds[(r0+r)*17 + l15] = acc[r];
    }
    __syncthreads();
    {
      int gb = m_*17 + q_*4, cb = bk*16 + q_*4;
      float gi = g_lds[gb+0] + bE[cb+0];
      float gf = g_lds[gb+1] + bE[cb+1];
      float gg = g_lds[gb+2] + bE[cb+2];
      float go = g_lds[gb+3] + bE[cb+3];
      float cold = cf[m_*HH + jh];
      float cn = sigm(gf)*cold + sigm(gi)*tanhf(gg);
      float hn = sigm(go)*tanhf(cn);
      cf[m_*HH + jh] = cn;
      st_h_swz(hWg, m_, jh, hn);
      st_b16_sc(encB + ((size_t)m_*LL + t)*HH + jh, hn);
    }
    gbar(flags, ++bar, bk);
  }

  // ================= phase S: static attention =================
  // softmax is h-independent: scores = score_d[b,l] + (h.Wh)[b] + bias ->
  // per-row constant shift cancels in softmax.
  {
    int b = bk >> 2, qq = bk & 3;
    for (int i = 0; i < 20; ++i) {
      int l = wv*20 + i;
      const __bf16* er = encB + ((size_t)b*LL + l)*HH + ln*16;
      bf16x8 e0 = *(const bf16x8*)(er);
      bf16x8 e1 = *(const bf16x8*)(er + 8);
      float part = 0.f;
#pragma unroll
      for (int j = 0; j < 8; ++j) {
        part += (float)e0[j] * attn_w[ln*16 + j];
        part += (float)e1[j] * attn_w[ln*16 + 8 + j];
      }
      part = wred_sum(part);
      if (ln == 0) sc_sh[l] = part;
    }
    __syncthreads();
    if (wv == 0) {
      int len = demlen[b];
      float s0 = (ln < len) ? sc_sh[ln] : -1e30f;
      float s1 = (ln < 16 && 64+ln < len) ? sc_sh[64+ln] : -1e30f;
      float mx = wred_max(fmaxf(s0, s1));
      float e0 = __expf(s0 - mx);
      float e1 = (ln < 16) ? __expf(s1 - mx) : 0.f;
      float inv = 1.f / wred_sum(e0 + e1);
      w_sh[ln] = e0 * inv;
      if (ln < 16) w_sh[64+ln] = e1 * inv;
    }
    __syncthreads();
    int col = qq*256 + tid;
    float a = 0.f;
    const __bf16* eb = encB + (size_t)b*LL*HH + col;
#pragma unroll 4
    for (int l = 0; l < LL; ++l) a += w_sh[l] * (float)eb[(size_t)l*HH];
    st_b16_sc(attnS + (size_t)b*HH + col, a);
    // decoder state init: h0 -> dslot0 (swizzled), c0 -> private cf
    for (int i = gtid; i < BB*HH; i += NB*NT) {
      int row = i >> 10;
      int byte = (i*2) ^ ((row & 7) << 4);
      st_b16_sc((__bf16*)((char*)hrotD + byte), h0[i]);
    }
    cf[m_*HH + jh] = c0[m_*HH + jh];
  }
  gbar(flags, ++bar, bk);

  // ================= phase X: x_all = relu([attn|obs_t]@combW^T + b) =========
  {
    int g = bk*4 + wv;
    for (int i = 0; i < 10; ++i) {
      int ti = i*1024 + g;            // 0..10239
      int mt = ti >> 6, nt = ti & 63; // 160 m-tiles x 64 n-tiles
      f32x4 acc = {0.f,0.f,0.f,0.f};
      const __bf16* brow = wComb + (size_t)(nt*16 + l15)*KCOMB;
      int r = mt*16 + l15, bb = r & 63;
      const __bf16* aat = attnS + (size_t)bb*HH;
      const __bf16* ast = stateB + (size_t)r*DD;
#pragma unroll 8
      for (int kk = 0; kk < KCOMB; kk += 32) {
        int k0 = kk + klane;
        bf16x8 af = (k0 < HH) ? *(const bf16x8*)(aat + k0)
                              : *(const bf16x8*)(ast + (k0-HH));
        acc = __builtin_amdgcn_mfma_f32_16x16x32_bf16(af, *(const bf16x8*)(brow + k0), acc, 0,0,0);
      }
      int col = nt*16 + l15;
      float cb = comb_b[col];
      int r0 = mt*16 + lhi*4;
#pragma unroll
      for (int rr = 0; rr < 4; ++rr)
        st_b16_sc(xall + (size_t)(r0+rr)*HH + col, fmaxf(acc[rr]+cb, 0.f));
    }
  }
  gbar(flags, ++bar, bk);

  // ================= decoder: 40 steps =================
  for (int t = 0; t < TT; ++t) {
    const __bf16* hRg = hrotD + (size_t)t*BB*HH;
    char*         hWg = (char*)(hrotD + (size_t)(t+1)*BB*HH);

    {
      const bf16x8* gs = (const bf16x8*)hRg;
      bf16x8* ls = (bf16x8*)lds_h;
#pragma unroll
      for (int rnd = 0; rnd < 4; ++rnd) {
        bf16x8 tmp[8];
#pragma unroll
        for (int u = 0; u < 8; ++u) tmp[u] = gs[(rnd*8+u)*NT + tid];
#pragma unroll
        for (int u = 0; u < 8; ++u) ls[(rnd*8+u)*NT + tid] = tmp[u];
      }
    }

    f32x4 acc = {0.f,0.f,0.f,0.f};
    const __bf16* brow = wLstm + (size_t)(bk*16 + l15)*KLSTM;
    const __bf16* xrow = xall + (size_t)t*BB*HH + (size_t)ar*HH;
    // x part (global L2, overlaps staging)
#pragma unroll 8
    for (int kk = 0; kk < HH; kk += 32) {
      int k0 = kk + klane;
      acc = __builtin_amdgcn_mfma_f32_16x16x32_bf16(*(const bf16x8*)(xrow + k0),
                                                    *(const bf16x8*)(brow + k0), acc, 0,0,0);
    }
    __syncthreads();
    // h part (LDS swizzled)
#pragma unroll 8
    for (int kk = 0; kk < HH; kk += 32) {
      int k0 = kk + klane;
      int off = (ar*2048 + k0*2) ^ ((ar & 7) << 4);
      acc = __builtin_amdgcn_mfma_f32_16x16x32_bf16(*(const bf16x8*)(lds_h + off),
                                                    *(const bf16x8*)(brow + HH + k0), acc, 0,0,0);
    }
    {
      int r0 = wv*16 + lhi*4;
#pragma unroll
      for (int r = 0; r < 4; ++r) g_lds[(r0+r)*17 + l15] = acc[r];
    }
    __syncthreads();
    {
      int gb = m_*17 + q_*4, cb = bk*16 + q_*4;
      float gi = g_lds[gb+0] + bL[cb+0];
      float gf = g_lds[gb+1] + bL[cb+1];
      float gg = g_lds[gb+2] + bL[cb+2];
      float go = g_lds[gb+3] + bL[cb+3];
      float cold = cf[m_*HH + jh];
      float cn = sigm(gf)*cold + sigm(gi)*tanhf(gg);
      float hn = sigm(go)*tanhf(cn);
      cf[m_*HH + jh] = cn;
      st_h_swz(hWg, m_, jh, hn);
      st_b16_sc(hdec + ((size_t)t*BB + m_)*HH + jh, hn);
      if (t == TT-1) out[QSZ + m_*HH + jh] = hn;   // exact fp32 final h
    }
    gbar(flags, ++bar, bk);
  }

  // final c (block-private cols, exact fp32)
  out[QSZ + BB*HH + m_*HH + jh] = cf[m_*HH + jh];

  // ================= epilogue: m = hdec @ midW^T + mid_b =================
  {
    int g = bk*4 + wv;
    for (int i = 0; i < 10; ++i) {
      int ti = i*1024 + g;
      int mt = ti >> 6, nt = ti & 63;
      f32x4 acc = {0.f,0.f,0.f,0.f};
      const __bf16* brow = wMid + (size_t)(nt*16 + l15)*HH;
      const __bf16* arow2 = hdec + (size_t)(mt*16 + l15)*HH;
#pragma unroll 8
      for (int kk = 0; kk < HH; kk += 32) {
        int k0 = kk + klane;
        acc = __builtin_amdgcn_mfma_f32_16x16x32_bf16(*(const bf16x8*)(arow2 + k0),
                                                      *(const bf16x8*)(brow + k0), acc, 0,0,0);
      }
      int col = nt*16 + l15;
      float mb = mid_b[col];
      int r0 = mt*16 + lhi*4;
#pragma unroll
      for (int rr = 0; rr < 4; ++rr)
        st_b16_sc(mf + (size_t)(r0+rr)*HH + col, acc[rr]+mb);
    }
  }
  gbar(flags, ++bar, bk);

  // ================= q = mf @ outW^T + out_b =================
  {
    int g = bk*4 + wv;
    for (int i = 0; i < 3; ++i) {
      int row = i*1024 + g;
      if (row < TT*BB) {
        const __bf16* mr = mf + (size_t)row*HH;
        float mreg[16];
#pragma unroll
        for (int k = 0; k < 16; ++k) mreg[k] = (float)mr[ln + 64*k];
        for (int a = 0; a < AA; ++a) {
          float p = 0.f;
#pragma unroll
          for (int k = 0; k < 16; ++k) p += mreg[k] * out_w[(size_t)a*HH + ln + 64*k];
          p = wred_sum(p);
          if (ln == 0) out[(size_t)row*AA + a] = p + out_b[a];
        }
      }
    }
  }
}

// ---------------- host launch ----------------
extern "C" void kernel_launch(void* const* d_in, const int* in_sizes, int n_in,
                              void* d_out, int out_size, void* d_ws, size_t ws_size,
                              hipStream_t stream) {
  (void)in_sizes; (void)n_in; (void)out_size; (void)ws_size;
  const float* state    = (const float*)d_in[0];
  const float* demo     = (const float*)d_in[1];
  const int*   demlen   = (const int*)d_in[2];
  const float* h0       = (const float*)d_in[3];
  const float* c0       = (const float*)d_in[4];
  const float* enc_wih  = (const float*)d_in[5];
  const float* enc_whh  = (const float*)d_in[6];
  const float* enc_bih  = (const float*)d_in[7];
  const float* enc_bhh  = (const float*)d_in[8];
  const float* attn_w   = (const float*)d_in[9];
  const float* comb_w   = (const float*)d_in[11];
  const float* comb_b   = (const float*)d_in[12];
  const float* lstm_wih = (const float*)d_in[13];
  const float* lstm_whh = (const float*)d_in[14];
  const float* lstm_bih = (const float*)d_in[15];
  const float* lstm_bhh = (const float*)d_in[16];
  const float* mid_w    = (const float*)d_in[17];
  const float* mid_b    = (const float*)d_in[18];
  const float* out_w    = (const float*)d_in[19];
  const float* out_b    = (const float*)d_in[20];
  char* ws = (char*)d_ws;

  (void)hipMemsetAsync(ws + OFF_BAR, 0, BAR_BYTES, stream);
  k_pack_enc <<<G4H, 256, 0, stream>>>(enc_wih, enc_whh, enc_bih, enc_bhh,
                                       (__bf16*)(ws + OFF_WENC), (float*)(ws + OFF_BIASE));
  k_pack_lstm<<<G4H, 256, 0, stream>>>(lstm_wih, lstm_whh, lstm_bih, lstm_bhh,
                                       (__bf16*)(ws + OFF_WLSTM), (float*)(ws + OFF_BIASL));
  k_conv<<<(HH*KCOMB + 255)/256, 256, 0, stream>>>(comb_w, (__bf16*)(ws + OFF_WCOMB), HH*KCOMB);
  k_conv<<<(HH*HH   + 255)/256, 256, 0, stream>>>(mid_w,  (__bf16*)(ws + OFF_WMID),  HH*HH);
  k_conv<<<(BB*LL*DD + 255)/256, 256, 0, stream>>>(demo,  (__bf16*)(ws + OFF_DEMO),  BB*LL*DD);
  k_conv<<<(TT*BB*DD + 255)/256, 256, 0, stream>>>(state, (__bf16*)(ws + OFF_STATE), TT*BB*DD);
  k_main<<<NB, NT, 0, stream>>>(demlen, h0, c0, attn_w, comb_b, mid_b,
                                out_w, out_b, (float*)d_out, ws);
}

// Round 6
// 2240.907 us; speedup vs baseline: 2.3606x; 1.0871x over previous
//
#include <hip/hip_runtime.h>
#include <hip/hip_bf16.h>

// ---------------- problem dims ----------------
#define TT 40
#define BB 64
#define LL 80
#define DD 256
#define HH 1024
#define G4H 4096
#define AA 18
#define KENC 1280   // [demo(256) | h(1024)]
#define KLSTM 2048  // [x(1024) | h(1024)]
#define KCOMB 1280  // [attn(1024) | obs(256)]
#define NB 256
#define NT 256
#define QSZ (TT*BB*AA)

typedef __bf16 bf16x8 __attribute__((ext_vector_type(8)));
typedef float  f32x4  __attribute__((ext_vector_type(4)));

// ---------------- workspace layout (bytes) ----------------
#define OFF_WENC   ((size_t)0)
#define OFF_WLSTM  (OFF_WENC  + (size_t)G4H*KENC*2)
#define OFF_WCOMB  (OFF_WLSTM + (size_t)G4H*KLSTM*2)
#define OFF_WMID   (OFF_WCOMB + (size_t)HH*KCOMB*2)
#define OFF_BIASE  (OFF_WMID  + (size_t)HH*HH*2)
#define OFF_BIASL  (OFF_BIASE + (size_t)G4H*4)
#define OFF_DEMO   (OFF_BIASL + (size_t)G4H*4)
#define OFF_STATE  (OFF_DEMO  + (size_t)BB*LL*DD*2)
#define OFF_ENC    (OFF_STATE + (size_t)TT*BB*DD*2)
#define OFF_HDEC   (OFF_ENC   + (size_t)BB*LL*HH*2)
#define OFF_XALL   (OFF_HDEC  + (size_t)TT*BB*HH*2)
#define OFF_MF     (OFF_XALL  + (size_t)TT*BB*HH*2)
#define OFF_ATTNS  (OFF_MF    + (size_t)TT*BB*HH*2)
#define OFF_CF     (OFF_ATTNS + (size_t)BB*HH*2)
#define OFF_HROT   (OFF_CF    + (size_t)BB*HH*4)
#define NSLOT_E    81
#define NSLOT_D    41
#define OFF_BAR    (OFF_HROT  + (size_t)(NSLOT_E+NSLOT_D)*BB*HH*2)
#define FLAG_STRIDE 16          // dwords: 64B per flag
#define BAR_BYTES  (NB*FLAG_STRIDE*4)

// ---------------- helpers ----------------
__device__ __forceinline__ float sigm(float x){ return 1.f/(1.f+__expf(-x)); }

__device__ __forceinline__ float wred_sum(float v){
#pragma unroll
  for (int s=32; s>0; s>>=1) v += __shfl_xor(v, s, 64);
  return v;
}
__device__ __forceinline__ float wred_max(float v){
#pragma unroll
  for (int s=32; s>0; s>>=1) v = fmaxf(v, __shfl_xor(v, s, 64));
  return v;
}

__device__ __forceinline__ unsigned pack_bf16(float a, float b){
  unsigned short ua = __builtin_bit_cast(unsigned short, (__bf16)a);
  unsigned short ub = __builtin_bit_cast(unsigned short, (__bf16)b);
  return (unsigned)ua | ((unsigned)ub << 16);
}

// write-through (coherent) stores: visible at LLC, no stale L2 write-allocate
__device__ __forceinline__ void st_u32_sc(unsigned* p, unsigned v){
  __hip_atomic_store(p, v, __ATOMIC_RELAXED, __HIP_MEMORY_SCOPE_AGENT);
}
__device__ __forceinline__ void st_b16_sc(__bf16* p, float v){
  unsigned short u = __builtin_bit_cast(unsigned short, (__bf16)v);
  asm volatile("global_store_short %0, %1, off sc0 sc1"
               :: "v"(p), "v"((unsigned)u) : "memory");
}

// async global->LDS DMA, 16B per lane, lands at ldsbase + lane*16
__device__ __forceinline__ void gload_lds16(const void* g, void* l){
  __builtin_amdgcn_global_load_lds(
      (const __attribute__((address_space(1))) unsigned*)g,
      (__attribute__((address_space(3))) unsigned*)l, 16, 0, 0);
}

// split all-to-all flag barrier (no same-address contention, no invalidations)
__device__ __forceinline__ void gbar_arrive(unsigned* flags, unsigned target, int bk){
  __syncthreads();   // drains vmcnt -> this block's stores done
  if (threadIdx.x == 0) {
    __builtin_amdgcn_fence(__ATOMIC_RELEASE, "agent");
    __hip_atomic_store(flags + (size_t)bk*FLAG_STRIDE, target,
                       __ATOMIC_RELAXED, __HIP_MEMORY_SCOPE_AGENT);
  }
}
__device__ __forceinline__ void gbar_wait(unsigned* flags, unsigned target){
  if (threadIdx.x < 64) {
    unsigned long long spins = 0;
    for (;;) {
      unsigned a0 = __hip_atomic_load(flags + (size_t)threadIdx.x*FLAG_STRIDE,       __ATOMIC_RELAXED, __HIP_MEMORY_SCOPE_AGENT);
      unsigned a1 = __hip_atomic_load(flags + (size_t)(64+threadIdx.x)*FLAG_STRIDE,  __ATOMIC_RELAXED, __HIP_MEMORY_SCOPE_AGENT);
      unsigned a2 = __hip_atomic_load(flags + (size_t)(128+threadIdx.x)*FLAG_STRIDE, __ATOMIC_RELAXED, __HIP_MEMORY_SCOPE_AGENT);
      unsigned a3 = __hip_atomic_load(flags + (size_t)(192+threadIdx.x)*FLAG_STRIDE, __ATOMIC_RELAXED, __HIP_MEMORY_SCOPE_AGENT);
      bool ok = (a0 >= target) && (a1 >= target) && (a2 >= target) && (a3 >= target);
      if (__all((int)ok)) break;
      if (++spins > (1ull<<20)) break;   // fail loud, never hang
      __builtin_amdgcn_s_sleep(1);
    }
  }
  __syncthreads();
  asm volatile("" ::: "memory");
}

// ---------------- prologue kernels ----------------
// packed gate row p = blk*16 + jj*4 + gate  <->  orig row gate*H + blk*4 + jj
__global__ void k_pack_enc(const float* __restrict__ wih, const float* __restrict__ whh,
                           const float* __restrict__ bih, const float* __restrict__ bhh,
                           __bf16* __restrict__ dst, float* __restrict__ bias){
  int p = blockIdx.x;
  int gate = p & 3, jj = (p >> 2) & 3, bq = p >> 4;
  int orig = gate*HH + bq*4 + jj;
  if (threadIdx.x == 0) bias[p] = bih[orig] + bhh[orig];
  const float* s0 = wih + (size_t)orig*DD;
  const float* s1 = whh + (size_t)orig*HH;
  __bf16* d = dst + (size_t)p*KENC;
  for (int k = threadIdx.x; k < KENC; k += blockDim.x)
    d[k] = (__bf16)(k < DD ? s0[k] : s1[k-DD]);
}
__global__ void k_pack_lstm(const float* __restrict__ wih, const float* __restrict__ whh,
                            const float* __restrict__ bih, const float* __restrict__ bhh,
                            __bf16* __restrict__ dst, float* __restrict__ bias){
  int p = blockIdx.x;
  int gate = p & 3, jj = (p >> 2) & 3, bq = p >> 4;
  int orig = gate*HH + bq*4 + jj;
  if (threadIdx.x == 0) bias[p] = bih[orig] + bhh[orig];
  const float* s0 = wih + (size_t)orig*HH;
  const float* s1 = whh + (size_t)orig*HH;
  __bf16* d = dst + (size_t)p*KLSTM;
  for (int k = threadIdx.x; k < KLSTM; k += blockDim.x)
    d[k] = (__bf16)(k < HH ? s0[k] : s1[k-HH]);
}
__global__ void k_conv(const float* __restrict__ src, __bf16* __restrict__ dst, int n){
  int i = blockIdx.x*blockDim.x + threadIdx.x;
  if (i < n) dst[i] = (__bf16)src[i];
}

// ---------------- persistent main kernel ----------------
__global__ __launch_bounds__(NT, 1)
void k_main(const int* __restrict__ demlen,
            const float* __restrict__ h0, const float* __restrict__ c0,
            const float* __restrict__ attn_w,
            const float* __restrict__ comb_b, const float* __restrict__ mid_b,
            const float* __restrict__ out_w, const float* __restrict__ out_b,
            float* __restrict__ out, char* __restrict__ ws){
  const int bk = blockIdx.x, tid = threadIdx.x;
  const int wv = tid >> 6, ln = tid & 63;
  const int l15 = ln & 15, lhi = ln >> 4;
  const int klane = lhi * 8;
  const int gtid = bk*NT + tid;

  __bf16* wEnc  = (__bf16*)(ws + OFF_WENC);
  __bf16* wLstm = (__bf16*)(ws + OFF_WLSTM);
  __bf16* wComb = (__bf16*)(ws + OFF_WCOMB);
  __bf16* wMid  = (__bf16*)(ws + OFF_WMID);
  const float* bE = (const float*)(ws + OFF_BIASE);
  const float* bL = (const float*)(ws + OFF_BIASL);
  __bf16* demoC = (__bf16*)(ws + OFF_DEMO);
  __bf16* stateB= (__bf16*)(ws + OFF_STATE);
  __bf16* encB  = (__bf16*)(ws + OFF_ENC);
  __bf16* hdec  = (__bf16*)(ws + OFF_HDEC);
  __bf16* xall  = (__bf16*)(ws + OFF_XALL);
  __bf16* mf    = (__bf16*)(ws + OFF_MF);
  __bf16* attnS = (__bf16*)(ws + OFF_ATTNS);
  float*  cf    = (float*)(ws + OFF_CF);
  __bf16* hrotE = (__bf16*)(ws + OFF_HROT);
  __bf16* hrotD = hrotE + (size_t)NSLOT_E*BB*HH;
  unsigned* flags = (unsigned*)(ws + OFF_BAR);

  __shared__ __align__(16) char lds_h[BB*HH*2];   // staged h (swizzled content)
  __shared__ float g_lds[BB*17];
  __shared__ float sc_sh[LL];
  __shared__ float w_sh[LL];

  unsigned bar = 0;
  const int m_ = tid >> 1, q2 = tid & 1;   // elementwise (tid<128): batch, col-pair
  const int j0_ = bk*4 + 2*q2;             // first of this thread's 2 h cols
  const int ar = wv*16 + l15;              // this lane's A row (batch)

  // ---- init: zero enc h slot 0 + private cf cols ----
  for (int i = gtid; i < BB*HH/2; i += NB*NT) st_u32_sc((unsigned*)hrotE + i, 0u);
  if (tid < 128) { cf[m_*HH + j0_] = 0.f; cf[m_*HH + j0_ + 1] = 0.f; }
  ++bar; gbar_arrive(flags, bar, bk);

  // ================= encoder: 80 steps =================
  for (int t = 0; t < LL; ++t) {
    // hoisted static loads (demo A-frags + full B-weight frags) overlap the poll
    bf16x8 dv[8], bw[8];
    const __bf16* arow = demoC + ((size_t)ar*LL + t)*DD;
    const __bf16* brow = wEnc + (size_t)(bk*16 + l15)*KENC;
#pragma unroll
    for (int u = 0; u < 8; ++u) dv[u] = *(const bf16x8*)(arow + u*32 + klane);
#pragma unroll
    for (int u = 0; u < 8; ++u) bw[u] = *(const bf16x8*)(brow + u*32 + klane);
    __builtin_amdgcn_sched_barrier(0);
    gbar_wait(flags, bar);

    // stage h_t -> LDS via async DMA (deep queue, no VGPR round-trip)
    {
      const char* hRg = (const char*)(hrotE + (size_t)t*BB*HH);
#pragma unroll
      for (int u = 0; u < 32; ++u) {
        int chunk = u*4 + wv;
        gload_lds16(hRg + chunk*1024 + ln*16, lds_h + chunk*1024);
      }
    }
    __builtin_amdgcn_sched_barrier(0);

    f32x4 acc = {0.f,0.f,0.f,0.f};
#pragma unroll
    for (int u = 0; u < 8; ++u)
      acc = __builtin_amdgcn_mfma_f32_16x16x32_bf16(dv[u], bw[u], acc, 0,0,0);
    __syncthreads();   // staging DMA complete (vmcnt0) across all waves
#pragma unroll 8
    for (int kk = 0; kk < HH; kk += 32) {
      int k0 = kk + klane;
      int off = (ar*2048 + k0*2) ^ ((ar & 7) << 4);
      acc = __builtin_amdgcn_mfma_f32_16x16x32_bf16(*(const bf16x8*)(lds_h + off),
                                                    *(const bf16x8*)(brow + DD + k0), acc, 0,0,0);
    }
    {
      int r0 = wv*16 + lhi*4;
#pragma unroll
      for (int r = 0; r < 4; ++r) g_lds[(r0+r)*17 + l15] = acc[r];
    }
    __syncthreads();
    if (tid < 128) {
      char* hWg = (char*)(hrotE + (size_t)(t+1)*BB*HH);
      int gb = m_*17 + q2*8, cb = bk*16 + q2*8;
      float gi0 = g_lds[gb+0]+bE[cb+0], gf0 = g_lds[gb+1]+bE[cb+1];
      float gg0 = g_lds[gb+2]+bE[cb+2], go0 = g_lds[gb+3]+bE[cb+3];
      float gi1 = g_lds[gb+4]+bE[cb+4], gf1 = g_lds[gb+5]+bE[cb+5];
      float gg1 = g_lds[gb+6]+bE[cb+6], go1 = g_lds[gb+7]+bE[cb+7];
      float cA = cf[m_*HH + j0_], cB = cf[m_*HH + j0_ + 1];
      float cn0 = sigm(gf0)*cA + sigm(gi0)*tanhf(gg0);
      float cn1 = sigm(gf1)*cB + sigm(gi1)*tanhf(gg1);
      float hn0 = sigm(go0)*tanhf(cn0);
      float hn1 = sigm(go1)*tanhf(cn1);
      cf[m_*HH + j0_] = cn0; cf[m_*HH + j0_ + 1] = cn1;
      unsigned hp = pack_bf16(hn0, hn1);
      int byte = (m_*2048 + j0_*2) ^ ((m_ & 7) << 4);
      st_u32_sc((unsigned*)(hWg + byte), hp);
      st_u32_sc((unsigned*)(encB + ((size_t)m_*LL + t)*HH + j0_), hp);
    }
    ++bar; gbar_arrive(flags, bar, bk);
  }

  // ================= phase S: static attention =================
  // softmax is h-independent: scores = score_d[b,l] + (h.Wh)[b] -> per-row
  // constant shift cancels in softmax. Attn weights shared across all t.
  gbar_wait(flags, bar);
  {
    int b = bk >> 2, qq = bk & 3;
    for (int i = 0; i < 20; ++i) {
      int l = wv*20 + i;
      const __bf16* er = encB + ((size_t)b*LL + l)*HH + ln*16;
      bf16x8 e0 = *(const bf16x8*)(er);
      bf16x8 e1 = *(const bf16x8*)(er + 8);
      float part = 0.f;
#pragma unroll
      for (int j = 0; j < 8; ++j) {
        part += (float)e0[j] * attn_w[ln*16 + j];
        part += (float)e1[j] * attn_w[ln*16 + 8 + j];
      }
      part = wred_sum(part);
      if (ln == 0) sc_sh[l] = part;
    }
    __syncthreads();
    if (wv == 0) {
      int len = demlen[b];
      float s0 = (ln < len) ? sc_sh[ln] : -1e30f;
      float s1 = (ln < 16 && 64+ln < len) ? sc_sh[64+ln] : -1e30f;
      float mx = wred_max(fmaxf(s0, s1));
      float e0 = __expf(s0 - mx);
      float e1 = (ln < 16) ? __expf(s1 - mx) : 0.f;
      float inv = 1.f / wred_sum(e0 + e1);
      w_sh[ln] = e0 * inv;
      if (ln < 16) w_sh[64+ln] = e1 * inv;
    }
    __syncthreads();
    int col = qq*256 + tid;
    float a = 0.f;
    const __bf16* eb = encB + (size_t)b*LL*HH + col;
#pragma unroll 4
    for (int l = 0; l < LL; ++l) a += w_sh[l] * (float)eb[(size_t)l*HH];
    st_b16_sc(attnS + (size_t)b*HH + col, a);
    // decoder state init: h0 -> dslot0 (swizzled), c0 -> private cf
    for (int i = gtid; i < BB*HH; i += NB*NT) {
      int row = i >> 10;
      int byte = (i*2) ^ ((row & 7) << 4);
      st_b16_sc((__bf16*)((char*)hrotD + byte), h0[i]);
    }
    if (tid < 128) {
      cf[m_*HH + j0_]     = c0[m_*HH + j0_];
      cf[m_*HH + j0_ + 1] = c0[m_*HH + j0_ + 1];
    }
  }
  ++bar; gbar_arrive(flags, bar, bk);

  // ================= phase X: x_all = relu([attn|obs_t]@combW^T + b) =========
  gbar_wait(flags, bar);
  {
    int g = bk*4 + wv;
    for (int i = 0; i < 10; ++i) {
      int ti = i*1024 + g;            // 0..10239
      int mt = ti >> 6, nt = ti & 63; // 160 m-tiles x 64 n-tiles
      f32x4 acc = {0.f,0.f,0.f,0.f};
      const __bf16* brow = wComb + (size_t)(nt*16 + l15)*KCOMB;
      int r = mt*16 + l15, bb = r & 63;
      const __bf16* aat = attnS + (size_t)bb*HH;
      const __bf16* ast = stateB + (size_t)r*DD;
#pragma unroll 8
      for (int kk = 0; kk < KCOMB; kk += 32) {
        int k0 = kk + klane;
        bf16x8 af = (k0 < HH) ? *(const bf16x8*)(aat + k0)
                              : *(const bf16x8*)(ast + (k0-HH));
        acc = __builtin_amdgcn_mfma_f32_16x16x32_bf16(af, *(const bf16x8*)(brow + k0), acc, 0,0,0);
      }
      int col = nt*16 + l15;
      float cb = comb_b[col];
      int r0 = mt*16 + lhi*4;
#pragma unroll
      for (int rr = 0; rr < 4; ++rr)
        st_b16_sc(xall + (size_t)(r0+rr)*HH + col, fmaxf(acc[rr]+cb, 0.f));
    }
  }
  ++bar; gbar_arrive(flags, bar, bk);
  gbar_wait(flags, bar);   // full barrier: decoder t=0's hoisted loads need X done

  // ================= decoder: 40 steps =================
  for (int t = 0; t < TT; ++t) {
    bf16x8 xv[32], bw[32];
    const __bf16* xrow = xall + ((size_t)t*BB + ar)*HH;
    const __bf16* brow = wLstm + (size_t)(bk*16 + l15)*KLSTM;
#pragma unroll
    for (int u = 0; u < 32; ++u) xv[u] = *(const bf16x8*)(xrow + u*32 + klane);
#pragma unroll
    for (int u = 0; u < 32; ++u) bw[u] = *(const bf16x8*)(brow + u*32 + klane);
    __builtin_amdgcn_sched_barrier(0);
    gbar_wait(flags, bar);

    {
      const char* hRg = (const char*)(hrotD + (size_t)t*BB*HH);
#pragma unroll
      for (int u = 0; u < 32; ++u) {
        int chunk = u*4 + wv;
        gload_lds16(hRg + chunk*1024 + ln*16, lds_h + chunk*1024);
      }
    }
    __builtin_amdgcn_sched_barrier(0);

    f32x4 acc = {0.f,0.f,0.f,0.f};
#pragma unroll
    for (int u = 0; u < 32; ++u)
      acc = __builtin_amdgcn_mfma_f32_16x16x32_bf16(xv[u], bw[u], acc, 0,0,0);
    __syncthreads();   // staging complete
#pragma unroll 8
    for (int kk = 0; kk < HH; kk += 32) {
      int k0 = kk + klane;
      int off = (ar*2048 + k0*2) ^ ((ar & 7) << 4);
      acc = __builtin_amdgcn_mfma_f32_16x16x32_bf16(*(const bf16x8*)(lds_h + off),
                                                    *(const bf16x8*)(brow + HH + k0), acc, 0,0,0);
    }
    {
      int r0 = wv*16 + lhi*4;
#pragma unroll
      for (int r = 0; r < 4; ++r) g_lds[(r0+r)*17 + l15] = acc[r];
    }
    __syncthreads();
    if (tid < 128) {
      char* hWg = (char*)(hrotD + (size_t)(t+1)*BB*HH);
      int gb = m_*17 + q2*8, cb = bk*16 + q2*8;
      float gi0 = g_lds[gb+0]+bL[cb+0], gf0 = g_lds[gb+1]+bL[cb+1];
      float gg0 = g_lds[gb+2]+bL[cb+2], go0 = g_lds[gb+3]+bL[cb+3];
      float gi1 = g_lds[gb+4]+bL[cb+4], gf1 = g_lds[gb+5]+bL[cb+5];
      float gg1 = g_lds[gb+6]+bL[cb+6], go1 = g_lds[gb+7]+bL[cb+7];
      float cA = cf[m_*HH + j0_], cB = cf[m_*HH + j0_ + 1];
      float cn0 = sigm(gf0)*cA + sigm(gi0)*tanhf(gg0);
      float cn1 = sigm(gf1)*cB + sigm(gi1)*tanhf(gg1);
      float hn0 = sigm(go0)*tanhf(cn0);
      float hn1 = sigm(go1)*tanhf(cn1);
      cf[m_*HH + j0_] = cn0; cf[m_*HH + j0_ + 1] = cn1;
      unsigned hp = pack_bf16(hn0, hn1);
      int byte = (m_*2048 + j0_*2) ^ ((m_ & 7) << 4);
      st_u32_sc((unsigned*)(hWg + byte), hp);
      st_u32_sc((unsigned*)(hdec + ((size_t)t*BB + m_)*HH + j0_), hp);
      if (t == TT-1) {   // exact fp32 final h straight from registers
        out[QSZ + m_*HH + j0_]     = hn0;
        out[QSZ + m_*HH + j0_ + 1] = hn1;
      }
    }
    ++bar; gbar_arrive(flags, bar, bk);
  }

  // final c (block-private cols, exact fp32)
  if (tid < 128) {
    out[QSZ + BB*HH + m_*HH + j0_]     = cf[m_*HH + j0_];
    out[QSZ + BB*HH + m_*HH + j0_ + 1] = cf[m_*HH + j0_ + 1];
  }

  // ================= epilogue: m = hdec @ midW^T + mid_b =================
  gbar_wait(flags, bar);
  {
    int g = bk*4 + wv;
    for (int i = 0; i < 10; ++i) {
      int ti = i*1024 + g;
      int mt = ti >> 6, nt = ti & 63;
      f32x4 acc = {0.f,0.f,0.f,0.f};
      const __bf16* brow = wMid + (size_t)(nt*16 + l15)*HH;
      const __bf16* arow2 = hdec + (size_t)(mt*16 + l15)*HH;
#pragma unroll 8
      for (int kk = 0; kk < HH; kk += 32) {
        int k0 = kk + klane;
        acc = __builtin_amdgcn_mfma_f32_16x16x32_bf16(*(const bf16x8*)(arow2 + k0),
                                                      *(const bf16x8*)(brow + k0), acc, 0,0,0);
      }
      int col = nt*16 + l15;
      float mb = mid_b[col];
      int r0 = mt*16 + lhi*4;
#pragma unroll
      for (int rr = 0; rr < 4; ++rr)
        st_b16_sc(mf + (size_t)(r0+rr)*HH + col, acc[rr]+mb);
    }
  }
  ++bar; gbar_arrive(flags, bar, bk);

  // ================= q = mf @ outW^T + out_b =================
  gbar_wait(flags, bar);
  {
    int g = bk*4 + wv;
    for (int i = 0; i < 3; ++i) {
      int row = i*1024 + g;
      if (row < TT*BB) {
        const __bf16* mr = mf + (size_t)row*HH;
        float mreg[16];
#pragma unroll
        for (int k = 0; k < 16; ++k) mreg[k] = (float)mr[ln + 64*k];
        for (int a = 0; a < AA; ++a) {
          float p = 0.f;
#pragma unroll
          for (int k = 0; k < 16; ++k) p += mreg[k] * out_w[(size_t)a*HH + ln + 64*k];
          p = wred_sum(p);
          if (ln == 0) out[(size_t)row*AA + a] = p + out_b[a];
        }
      }
    }
  }
}

// ---------------- host launch ----------------
extern "C" void kernel_launch(void* const* d_in, const int* in_sizes, int n_in,
                              void* d_out, int out_size, void* d_ws, size_t ws_size,
                              hipStream_t stream) {
  (void)in_sizes; (void)n_in; (void)out_size; (void)ws_size;
  const float* state    = (const float*)d_in[0];
  const float* demo     = (const float*)d_in[1];
  const int*   demlen   = (const int*)d_in[2];
  const float* h0       = (const float*)d_in[3];
  const float* c0       = (const float*)d_in[4];
  const float* enc_wih  = (const float*)d_in[5];
  const float* enc_whh  = (const float*)d_in[6];
  const float* enc_bih  = (const float*)d_in[7];
  const float* enc_bhh  = (const float*)d_in[8];
  const float* attn_w   = (const float*)d_in[9];
  const float* comb_w   = (const float*)d_in[11];
  const float* comb_b   = (const float*)d_in[12];
  const float* lstm_wih = (const float*)d_in[13];
  const float* lstm_whh = (const float*)d_in[14];
  const float* lstm_bih = (const float*)d_in[15];
  const float* lstm_bhh = (const float*)d_in[16];
  const float* mid_w    = (const float*)d_in[17];
  const float* mid_b    = (const float*)d_in[18];
  const float* out_w    = (const float*)d_in[19];
  const float* out_b    = (const float*)d_in[20];
  char* ws = (char*)d_ws;

  (void)hipMemsetAsync(ws + OFF_BAR, 0, BAR_BYTES, stream);
  k_pack_enc <<<G4H, 256, 0, stream>>>(enc_wih, enc_whh, enc_bih, enc_bhh,
                                       (__bf16*)(ws + OFF_WENC), (float*)(ws + OFF_BIASE));
  k_pack_lstm<<<G4H, 256, 0, stream>>>(lstm_wih, lstm_whh, lstm_bih, lstm_bhh,
                                       (__bf16*)(ws + OFF_WLSTM), (float*)(ws + OFF_BIASL));
  k_conv<<<(HH*KCOMB + 255)/256, 256, 0, stream>>>(comb_w, (__bf16*)(ws + OFF_WCOMB), HH*KCOMB);
  k_conv<<<(HH*HH   + 255)/256, 256, 0, stream>>>(mid_w,  (__bf16*)(ws + OFF_WMID),  HH*HH);
  k_conv<<<(BB*LL*DD + 255)/256, 256, 0, stream>>>(demo,  (__bf16*)(ws + OFF_DEMO),  BB*LL*DD);
  k_conv<<<(TT*BB*DD + 255)/256, 256, 0, stream>>>(state, (__bf16*)(ws + OFF_STATE), TT*BB*DD);
  k_main<<<NB, NT, 0, stream>>>(demlen, h0, c0, attn_w, comb_b, mid_b,
                                out_w, out_b, (float*)d_out, ws);
}

// Round 7
// 2125.295 us; speedup vs baseline: 2.4890x; 1.0544x over previous
//
#include <hip/hip_runtime.h>
#include <hip/hip_bf16.h>

// ---------------- problem dims ----------------
#define TT 40
#define BB 64
#define LL 80
#define DD 256
#define HH 1024
#define G4H 4096
#define AA 18
#define KENC 1280   // [demo(256) | h(1024)]
#define KLSTM 2048  // [x(1024) | h(1024)]
#define KCOMB 1280  // [attn(1024) | obs(256)]
#define NB 256
#define NT 512
#define QSZ (TT*BB*AA)

typedef __bf16 bf16x8 __attribute__((ext_vector_type(8)));
typedef float  f32x4  __attribute__((ext_vector_type(4)));

// ---------------- workspace layout (bytes) ----------------
#define OFF_WENC   ((size_t)0)
#define OFF_WLSTM  (OFF_WENC  + (size_t)G4H*KENC*2)
#define OFF_WCOMB  (OFF_WLSTM + (size_t)G4H*KLSTM*2)
#define OFF_WMID   (OFF_WCOMB + (size_t)HH*KCOMB*2)
#define OFF_BIASE  (OFF_WMID  + (size_t)HH*HH*2)
#define OFF_BIASL  (OFF_BIASE + (size_t)G4H*4)
#define OFF_DEMO   (OFF_BIASL + (size_t)G4H*4)
#define OFF_STATE  (OFF_DEMO  + (size_t)BB*LL*DD*2)
#define OFF_ENC    (OFF_STATE + (size_t)TT*BB*DD*2)
#define OFF_HDEC   (OFF_ENC   + (size_t)BB*LL*HH*2)
#define OFF_XALL   (OFF_HDEC  + (size_t)TT*BB*HH*2)
#define OFF_MF     (OFF_XALL  + (size_t)TT*BB*HH*2)
#define OFF_ATTNS  (OFF_MF    + (size_t)TT*BB*HH*2)
#define OFF_HROT   (OFF_ATTNS + (size_t)BB*HH*2)
#define NSLOT_E    81
#define NSLOT_D    41
#define OFF_BAR    (OFF_HROT  + (size_t)(NSLOT_E+NSLOT_D)*BB*HH*2)
#define FLAG_STRIDE 16          // dwords: 64B per flag
#define BAR_BYTES  (NB*FLAG_STRIDE*4)

// ---------------- helpers ----------------
__device__ __forceinline__ float sigm(float x){ return 1.f/(1.f+__expf(-x)); }

__device__ __forceinline__ float wred_sum(float v){
#pragma unroll
  for (int s=32; s>0; s>>=1) v += __shfl_xor(v, s, 64);
  return v;
}
__device__ __forceinline__ float wred_max(float v){
#pragma unroll
  for (int s=32; s>0; s>>=1) v = fmaxf(v, __shfl_xor(v, s, 64));
  return v;
}

__device__ __forceinline__ unsigned pack_bf16(float a, float b){
  unsigned short ua = __builtin_bit_cast(unsigned short, (__bf16)a);
  unsigned short ub = __builtin_bit_cast(unsigned short, (__bf16)b);
  return (unsigned)ua | ((unsigned)ub << 16);
}

// write-through (coherent) stores: visible at MALL, never stale in any L2
__device__ __forceinline__ void st_u32_sc(unsigned* p, unsigned v){
  __hip_atomic_store(p, v, __ATOMIC_RELAXED, __HIP_MEMORY_SCOPE_AGENT);
}
__device__ __forceinline__ void st_b16_sc(__bf16* p, float v){
  unsigned short u = __builtin_bit_cast(unsigned short, (__bf16)v);
  asm volatile("global_store_short %0, %1, off sc0 sc1"
               :: "v"(p), "v"((unsigned)u) : "memory");
}

// split all-to-all flag barrier (no same-address contention, no invalidations)
__device__ __forceinline__ void gbar_arrive(unsigned* flags, unsigned target, int bk){
  __syncthreads();   // drains vmcnt -> this block's stores done
  if (threadIdx.x == 0) {
    __builtin_amdgcn_fence(__ATOMIC_RELEASE, "agent");
    __hip_atomic_store(flags + (size_t)bk*FLAG_STRIDE, target,
                       __ATOMIC_RELAXED, __HIP_MEMORY_SCOPE_AGENT);
  }
}
__device__ __forceinline__ void gbar_wait(unsigned* flags, unsigned target){
  if (threadIdx.x < 64) {
    unsigned long long spins = 0;
    for (;;) {
      unsigned a0 = __hip_atomic_load(flags + (size_t)threadIdx.x*FLAG_STRIDE,       __ATOMIC_RELAXED, __HIP_MEMORY_SCOPE_AGENT);
      unsigned a1 = __hip_atomic_load(flags + (size_t)(64+threadIdx.x)*FLAG_STRIDE,  __ATOMIC_RELAXED, __HIP_MEMORY_SCOPE_AGENT);
      unsigned a2 = __hip_atomic_load(flags + (size_t)(128+threadIdx.x)*FLAG_STRIDE, __ATOMIC_RELAXED, __HIP_MEMORY_SCOPE_AGENT);
      unsigned a3 = __hip_atomic_load(flags + (size_t)(192+threadIdx.x)*FLAG_STRIDE, __ATOMIC_RELAXED, __HIP_MEMORY_SCOPE_AGENT);
      bool ok = (a0 >= target) && (a1 >= target) && (a2 >= target) && (a3 >= target);
      if (__all((int)ok)) break;
      if (++spins > (1ull<<20)) break;   // fail loud, never hang
      __builtin_amdgcn_s_sleep(1);
    }
  }
  __syncthreads();
  asm volatile("" ::: "memory");
}

// ---------------- prologue kernels ----------------
// packed gate row p = blk*16 + jj*4 + gate  <->  orig row gate*H + blk*4 + jj
__global__ void k_pack_enc(const float* __restrict__ wih, const float* __restrict__ whh,
                           const float* __restrict__ bih, const float* __restrict__ bhh,
                           __bf16* __restrict__ dst, float* __restrict__ bias){
  int p = blockIdx.x;
  int gate = p & 3, jj = (p >> 2) & 3, bq = p >> 4;
  int orig = gate*HH + bq*4 + jj;
  if (threadIdx.x == 0) bias[p] = bih[orig] + bhh[orig];
  const float* s0 = wih + (size_t)orig*DD;
  const float* s1 = whh + (size_t)orig*HH;
  __bf16* d = dst + (size_t)p*KENC;
  for (int k = threadIdx.x; k < KENC; k += blockDim.x)
    d[k] = (__bf16)(k < DD ? s0[k] : s1[k-DD]);
}
__global__ void k_pack_lstm(const float* __restrict__ wih, const float* __restrict__ whh,
                            const float* __restrict__ bih, const float* __restrict__ bhh,
                            __bf16* __restrict__ dst, float* __restrict__ bias){
  int p = blockIdx.x;
  int gate = p & 3, jj = (p >> 2) & 3, bq = p >> 4;
  int orig = gate*HH + bq*4 + jj;
  if (threadIdx.x == 0) bias[p] = bih[orig] + bhh[orig];
  const float* s0 = wih + (size_t)orig*HH;
  const float* s1 = whh + (size_t)orig*HH;
  __bf16* d = dst + (size_t)p*KLSTM;
  for (int k = threadIdx.x; k < KLSTM; k += blockDim.x)
    d[k] = (__bf16)(k < HH ? s0[k] : s1[k-HH]);
}
__global__ void k_conv(const float* __restrict__ src, __bf16* __restrict__ dst, int n){
  int i = blockIdx.x*blockDim.x + threadIdx.x;
  if (i < n) dst[i] = (__bf16)src[i];
}

// ---------------- persistent main kernel ----------------
// 8 waves/block: waves 0-3 = first K-half of the gate GEMM (m-tile wv&3),
// waves 4-7 = second K-half (same m-tile). Partial sums meet in g_lds/g_lds2.
__global__ __launch_bounds__(NT, 1)
void k_main(const int* __restrict__ demlen,
            const float* __restrict__ h0, const float* __restrict__ c0,
            const float* __restrict__ attn_w,
            const float* __restrict__ comb_b, const float* __restrict__ mid_b,
            const float* __restrict__ out_w, const float* __restrict__ out_b,
            float* __restrict__ out, char* __restrict__ ws){
  const int bk = blockIdx.x, tid = threadIdx.x;
  const int wv = tid >> 6, ln = tid & 63;
  const int l15 = ln & 15, lhi = ln >> 4;
  const int klane = lhi * 8;
  const int gtid = bk*NT + tid;

  __bf16* wEnc  = (__bf16*)(ws + OFF_WENC);
  __bf16* wLstm = (__bf16*)(ws + OFF_WLSTM);
  __bf16* wComb = (__bf16*)(ws + OFF_WCOMB);
  __bf16* wMid  = (__bf16*)(ws + OFF_WMID);
  const float* bE = (const float*)(ws + OFF_BIASE);
  const float* bL = (const float*)(ws + OFF_BIASL);
  __bf16* demoC = (__bf16*)(ws + OFF_DEMO);
  __bf16* stateB= (__bf16*)(ws + OFF_STATE);
  __bf16* encB  = (__bf16*)(ws + OFF_ENC);
  __bf16* hdec  = (__bf16*)(ws + OFF_HDEC);
  __bf16* xall  = (__bf16*)(ws + OFF_XALL);
  __bf16* mf    = (__bf16*)(ws + OFF_MF);
  __bf16* attnS = (__bf16*)(ws + OFF_ATTNS);
  __bf16* hrotE = (__bf16*)(ws + OFF_HROT);
  __bf16* hrotD = hrotE + (size_t)NSLOT_E*BB*HH;
  unsigned* flags = (unsigned*)(ws + OFF_BAR);

  __shared__ float g_lds [BB*17];   // K-half 0 partial gates (64x16, pad 17)
  __shared__ float g_lds2[BB*17];   // K-half 1 partial gates
  __shared__ float sc_sh[LL];
  __shared__ float w_sh[LL];

  unsigned bar = 0;
  const int m_ = tid >> 1, q2 = tid & 1;   // elementwise (tid<128): batch, col-pair
  const int j0_ = bk*4 + 2*q2;             // first of this thread's 2 h cols
  const int mt = wv & 3;                   // m-tile (16 batch rows)
  const int am = mt*16 + l15;              // this lane's A row (batch)
  const int khalf = wv >> 2;               // 0 or 1: K-half

  float cfa = 0.f, cfb = 0.f;              // cell state in registers (tid<128)

  // ---- init: zero enc h slot 0 ----
  for (int i = gtid; i < BB*HH/2; i += NB*NT) st_u32_sc((unsigned*)hrotE + i, 0u);
  ++bar; gbar_arrive(flags, bar, bk);

  // ================= encoder: 80 steps, K split 640/640 =================
  for (int t = 0; t < LL; ++t) {
    gbar_wait(flags, bar);
    const __bf16* hR = hrotE + (size_t)t*BB*HH;
    const __bf16* brow = wEnc + (size_t)(bk*16 + l15)*KENC;
    const int kbase = khalf * 640;

    f32x4 acc = {0.f,0.f,0.f,0.f};
#pragma unroll 8
    for (int kk = 0; kk < 640; kk += 32) {
      int k0 = kbase + kk + klane;
      const __bf16* pa = (k0 < DD) ? demoC + ((size_t)am*LL + t)*DD + k0
                                   : hR + (size_t)am*HH + (k0 - DD);
      acc = __builtin_amdgcn_mfma_f32_16x16x32_bf16(*(const bf16x8*)pa,
                                                    *(const bf16x8*)(brow + k0), acc, 0,0,0);
    }
    {
      float* gl = khalf ? g_lds2 : g_lds;
      int r0 = mt*16 + lhi*4;
#pragma unroll
      for (int r = 0; r < 4; ++r) gl[(r0+r)*17 + l15] = acc[r];
    }
    __syncthreads();
    if (tid < 128) {
      char* hWg = (char*)(hrotE + (size_t)(t+1)*BB*HH);
      int gb = m_*17 + q2*8, cb = bk*16 + q2*8;
      float gi0 = g_lds[gb+0]+g_lds2[gb+0]+bE[cb+0], gf0 = g_lds[gb+1]+g_lds2[gb+1]+bE[cb+1];
      float gg0 = g_lds[gb+2]+g_lds2[gb+2]+bE[cb+2], go0 = g_lds[gb+3]+g_lds2[gb+3]+bE[cb+3];
      float gi1 = g_lds[gb+4]+g_lds2[gb+4]+bE[cb+4], gf1 = g_lds[gb+5]+g_lds2[gb+5]+bE[cb+5];
      float gg1 = g_lds[gb+6]+g_lds2[gb+6]+bE[cb+6], go1 = g_lds[gb+7]+g_lds2[gb+7]+bE[cb+7];
      float cn0 = sigm(gf0)*cfa + sigm(gi0)*tanhf(gg0);
      float cn1 = sigm(gf1)*cfb + sigm(gi1)*tanhf(gg1);
      float hn0 = sigm(go0)*tanhf(cn0);
      float hn1 = sigm(go1)*tanhf(cn1);
      cfa = cn0; cfb = cn1;
      unsigned hp = pack_bf16(hn0, hn1);
      st_u32_sc((unsigned*)(hWg + m_*2048 + j0_*2), hp);
      st_u32_sc((unsigned*)(encB + ((size_t)m_*LL + t)*HH + j0_), hp);
    }
    ++bar; gbar_arrive(flags, bar, bk);
  }

  // ================= phase S: static attention =================
  // softmax is h-independent: scores = score_d[b,l] + (h.Wh)[b] -> per-row
  // constant shift cancels in softmax. Attn weights shared across all t.
  gbar_wait(flags, bar);
  {
    int b = bk >> 2, qq = bk & 3;
    for (int i = 0; i < 10; ++i) {
      int l = wv*10 + i;
      const __bf16* er = encB + ((size_t)b*LL + l)*HH + ln*16;
      bf16x8 e0 = *(const bf16x8*)(er);
      bf16x8 e1 = *(const bf16x8*)(er + 8);
      float part = 0.f;
#pragma unroll
      for (int j = 0; j < 8; ++j) {
        part += (float)e0[j] * attn_w[ln*16 + j];
        part += (float)e1[j] * attn_w[ln*16 + 8 + j];
      }
      part = wred_sum(part);
      if (ln == 0) sc_sh[l] = part;
    }
    __syncthreads();
    if (wv == 0) {
      int len = demlen[b];
      float s0 = (ln < len) ? sc_sh[ln] : -1e30f;
      float s1 = (ln < 16 && 64+ln < len) ? sc_sh[64+ln] : -1e30f;
      float mx = wred_max(fmaxf(s0, s1));
      float e0 = __expf(s0 - mx);
      float e1 = (ln < 16) ? __expf(s1 - mx) : 0.f;
      float inv = 1.f / wred_sum(e0 + e1);
      w_sh[ln] = e0 * inv;
      if (ln < 16) w_sh[64+ln] = e1 * inv;
    }
    __syncthreads();
    if (tid < 256) {
      int col = qq*256 + tid;
      float a = 0.f;
      const __bf16* eb = encB + (size_t)b*LL*HH + col;
#pragma unroll 4
      for (int l = 0; l < LL; ++l) a += w_sh[l] * (float)eb[(size_t)l*HH];
      st_b16_sc(attnS + (size_t)b*HH + col, a);
    }
    // decoder state init: h0 -> dslot0, c0 -> registers
    for (int i = gtid; i < BB*HH/2; i += NB*NT) {
      int i2 = i*2;
      st_u32_sc((unsigned*)hrotD + i, pack_bf16(h0[i2], h0[i2+1]));
    }
    if (tid < 128) {
      cfa = c0[m_*HH + j0_];
      cfb = c0[m_*HH + j0_ + 1];
    }
  }
  ++bar; gbar_arrive(flags, bar, bk);

  // ================= phase X: x_all = relu([attn|obs_t]@combW^T + b) =========
  gbar_wait(flags, bar);
  {
    int g = bk*8 + wv;
    for (int i = 0; i < 5; ++i) {
      int ti = i*2048 + g;            // 0..10239
      int mtt = ti >> 6, nt = ti & 63; // 160 m-tiles x 64 n-tiles
      f32x4 acc = {0.f,0.f,0.f,0.f};
      const __bf16* brow = wComb + (size_t)(nt*16 + l15)*KCOMB;
      int r = mtt*16 + l15, bb = r & 63;
      const __bf16* aat = attnS + (size_t)bb*HH;
      const __bf16* ast = stateB + (size_t)r*DD;
#pragma unroll 8
      for (int kk = 0; kk < KCOMB; kk += 32) {
        int k0 = kk + klane;
        bf16x8 af = (k0 < HH) ? *(const bf16x8*)(aat + k0)
                              : *(const bf16x8*)(ast + (k0-HH));
        acc = __builtin_amdgcn_mfma_f32_16x16x32_bf16(af, *(const bf16x8*)(brow + k0), acc, 0,0,0);
      }
      int col = nt*16 + l15;
      float cb = comb_b[col];
      int r0 = mtt*16 + lhi*4;
#pragma unroll
      for (int rr = 0; rr < 4; ++rr)
        st_b16_sc(xall + (size_t)(r0+rr)*HH + col, fmaxf(acc[rr]+cb, 0.f));
    }
  }
  ++bar; gbar_arrive(flags, bar, bk);

  // ================= decoder: 40 steps, K split 1024/1024 =================
  for (int t = 0; t < TT; ++t) {
    gbar_wait(flags, bar);
    const __bf16* hR = hrotD + (size_t)t*BB*HH;
    const __bf16* brow = wLstm + (size_t)(bk*16 + l15)*KLSTM;
    const int kbase = khalf * HH;
    const __bf16* arow = khalf ? (hR + (size_t)am*HH)
                               : (xall + ((size_t)t*BB + am)*HH);

    f32x4 acc = {0.f,0.f,0.f,0.f};
#pragma unroll 8
    for (int kk = 0; kk < HH; kk += 32) {
      int k0 = kk + klane;
      acc = __builtin_amdgcn_mfma_f32_16x16x32_bf16(*(const bf16x8*)(arow + k0),
                                                    *(const bf16x8*)(brow + kbase + k0), acc, 0,0,0);
    }
    {
      float* gl = khalf ? g_lds2 : g_lds;
      int r0 = mt*16 + lhi*4;
#pragma unroll
      for (int r = 0; r < 4; ++r) gl[(r0+r)*17 + l15] = acc[r];
    }
    __syncthreads();
    if (tid < 128) {
      char* hWg = (char*)(hrotD + (size_t)(t+1)*BB*HH);
      int gb = m_*17 + q2*8, cb = bk*16 + q2*8;
      float gi0 = g_lds[gb+0]+g_lds2[gb+0]+bL[cb+0], gf0 = g_lds[gb+1]+g_lds2[gb+1]+bL[cb+1];
      float gg0 = g_lds[gb+2]+g_lds2[gb+2]+bL[cb+2], go0 = g_lds[gb+3]+g_lds2[gb+3]+bL[cb+3];
      float gi1 = g_lds[gb+4]+g_lds2[gb+4]+bL[cb+4], gf1 = g_lds[gb+5]+g_lds2[gb+5]+bL[cb+5];
      float gg1 = g_lds[gb+6]+g_lds2[gb+6]+bL[cb+6], go1 = g_lds[gb+7]+g_lds2[gb+7]+bL[cb+7];
      float cn0 = sigm(gf0)*cfa + sigm(gi0)*tanhf(gg0);
      float cn1 = sigm(gf1)*cfb + sigm(gi1)*tanhf(gg1);
      float hn0 = sigm(go0)*tanhf(cn0);
      float hn1 = sigm(go1)*tanhf(cn1);
      cfa = cn0; cfb = cn1;
      unsigned hp = pack_bf16(hn0, hn1);
      st_u32_sc((unsigned*)(hWg + m_*2048 + j0_*2), hp);
      st_u32_sc((unsigned*)(hdec + ((size_t)t*BB + m_)*HH + j0_), hp);
      if (t == TT-1) {   // exact fp32 final h straight from registers
        out[QSZ + m_*HH + j0_]     = hn0;
        out[QSZ + m_*HH + j0_ + 1] = hn1;
      }
    }
    ++bar; gbar_arrive(flags, bar, bk);
  }

  // final c (block-private cols, exact fp32 from registers)
  if (tid < 128) {
    out[QSZ + BB*HH + m_*HH + j0_]     = cfa;
    out[QSZ + BB*HH + m_*HH + j0_ + 1] = cfb;
  }

  // ================= epilogue: m = hdec @ midW^T + mid_b =================
  gbar_wait(flags, bar);
  {
    int g = bk*8 + wv;
    for (int i = 0; i < 5; ++i) {
      int ti = i*2048 + g;
      int mtt = ti >> 6, nt = ti & 63;
      f32x4 acc = {0.f,0.f,0.f,0.f};
      const __bf16* brow = wMid + (size_t)(nt*16 + l15)*HH;
      const __bf16* arow2 = hdec + (size_t)(mtt*16 + l15)*HH;
#pragma unroll 8
      for (int kk = 0; kk < HH; kk += 32) {
        int k0 = kk + klane;
        acc = __builtin_amdgcn_mfma_f32_16x16x32_bf16(*(const bf16x8*)(arow2 + k0),
                                                      *(const bf16x8*)(brow + k0), acc, 0,0,0);
      }
      int col = nt*16 + l15;
      float mb = mid_b[col];
      int r0 = mtt*16 + lhi*4;
#pragma unroll
      for (int rr = 0; rr < 4; ++rr)
        st_b16_sc(mf + (size_t)(r0+rr)*HH + col, acc[rr]+mb);
    }
  }
  ++bar; gbar_arrive(flags, bar, bk);

  // ================= q = mf @ outW^T + out_b =================
  gbar_wait(flags, bar);
  {
    int g = bk*8 + wv;
    for (int i = 0; i < 2; ++i) {
      int row = i*2048 + g;
      if (row < TT*BB) {
        const __bf16* mr = mf + (size_t)row*HH;
        float mreg[16];
#pragma unroll
        for (int k = 0; k < 16; ++k) mreg[k] = (float)mr[ln + 64*k];
        for (int a = 0; a < AA; ++a) {
          float p = 0.f;
#pragma unroll
          for (int k = 0; k < 16; ++k) p += mreg[k] * out_w[(size_t)a*HH + ln + 64*k];
          p = wred_sum(p);
          if (ln == 0) out[(size_t)row*AA + a] = p + out_b[a];
        }
      }
    }
  }
}

// ---------------- host launch ----------------
extern "C" void kernel_launch(void* const* d_in, const int* in_sizes, int n_in,
                              void* d_out, int out_size, void* d_ws, size_t ws_size,
                              hipStream_t stream) {
  (void)in_sizes; (void)n_in; (void)out_size; (void)ws_size;
  const float* state    = (const float*)d_in[0];
  const float* demo     = (const float*)d_in[1];
  const int*   demlen   = (const int*)d_in[2];
  const float* h0       = (const float*)d_in[3];
  const float* c0       = (const float*)d_in[4];
  const float* enc_wih  = (const float*)d_in[5];
  const float* enc_whh  = (const float*)d_in[6];
  const float* enc_bih  = (const float*)d_in[7];
  const float* enc_bhh  = (const float*)d_in[8];
  const float* attn_w   = (const float*)d_in[9];
  const float* comb_w   = (const float*)d_in[11];
  const float* comb_b   = (const float*)d_in[12];
  const float* lstm_wih = (const float*)d_in[13];
  const float* lstm_whh = (const float*)d_in[14];
  const float* lstm_bih = (const float*)d_in[15];
  const float* lstm_bhh = (const float*)d_in[16];
  const float* mid_w    = (const float*)d_in[17];
  const float* mid_b    = (const float*)d_in[18];
  const float* out_w    = (const float*)d_in[19];
  const float* out_b    = (const float*)d_in[20];
  char* ws = (char*)d_ws;

  (void)hipMemsetAsync(ws + OFF_BAR, 0, BAR_BYTES, stream);
  k_pack_enc <<<G4H, 256, 0, stream>>>(enc_wih, enc_whh, enc_bih, enc_bhh,
                                       (__bf16*)(ws + OFF_WENC), (float*)(ws + OFF_BIASE));
  k_pack_lstm<<<G4H, 256, 0, stream>>>(lstm_wih, lstm_whh, lstm_bih, lstm_bhh,
                                       (__bf16*)(ws + OFF_WLSTM), (float*)(ws + OFF_BIASL));
  k_conv<<<(HH*KCOMB + 255)/256, 256, 0, stream>>>(comb_w, (__bf16*)(ws + OFF_WCOMB), HH*KCOMB);
  k_conv<<<(HH*HH   + 255)/256, 256, 0, stream>>>(mid_w,  (__bf16*)(ws + OFF_WMID),  HH*HH);
  k_conv<<<(BB*LL*DD + 255)/256, 256, 0, stream>>>(demo,  (__bf16*)(ws + OFF_DEMO),  BB*LL*DD);
  k_conv<<<(TT*BB*DD + 255)/256, 256, 0, stream>>>(state, (__bf16*)(ws + OFF_STATE), TT*BB*DD);
  k_main<<<NB, NT, 0, stream>>>(demlen, h0, c0, attn_w, comb_b, mid_b,
                                out_w, out_b, (float*)d_out, ws);
}

// Round 8
// 1915.174 us; speedup vs baseline: 2.7621x; 1.1097x over previous
//
#include <hip/hip_runtime.h>
#include <hip/hip_bf16.h>

// ---------------- problem dims ----------------
#define TT 40
#define BB 64
#define LL 80
#define DD 256
#define HH 1024
#define G4H 4096
#define AA 18
#define KENC 1280   // [demo(256) | h(1024)]
#define KLSTM 2048  // [x(1024) | h(1024)]
#define KCOMB 1280  // [attn(1024) | obs(256)]
#define QSZ (TT*BB*AA)

typedef __bf16 bf16x8 __attribute__((ext_vector_type(8)));
typedef float  f32x4  __attribute__((ext_vector_type(4)));

// ---------------- workspace layout (bytes) ----------------
#define OFF_WENC   ((size_t)0)
#define OFF_WLSTM  (OFF_WENC  + (size_t)G4H*KENC*2)
#define OFF_WCOMB  (OFF_WLSTM + (size_t)G4H*KLSTM*2)
#define OFF_WMID   (OFF_WCOMB + (size_t)HH*KCOMB*2)
#define OFF_BIASE  (OFF_WMID  + (size_t)HH*HH*2)
#define OFF_BIASL  (OFF_BIASE + (size_t)G4H*4)
#define OFF_DEMO   (OFF_BIASL + (size_t)G4H*4)
#define OFF_STATE  (OFF_DEMO  + (size_t)BB*LL*DD*2)
#define OFF_ENC    (OFF_STATE + (size_t)TT*BB*DD*2)
#define OFF_HDEC   (OFF_ENC   + (size_t)BB*LL*HH*2)
#define OFF_XALL   (OFF_HDEC  + (size_t)TT*BB*HH*2)
#define OFF_MF     (OFF_XALL  + (size_t)TT*BB*HH*2)
#define OFF_ATTNS  (OFF_MF    + (size_t)TT*BB*HH*2)
#define OFF_CF     (OFF_ATTNS + (size_t)BB*HH*2)
#define OFF_HBUF   (OFF_CF    + (size_t)BB*HH*4)   // 4 slots (encA,encB,decA,decB)

// ---------------- helpers ----------------
__device__ __forceinline__ float sigm(float x){ return 1.f/(1.f+__expf(-x)); }

__device__ __forceinline__ float wred_sum(float v){
#pragma unroll
  for (int s=32; s>0; s>>=1) v += __shfl_xor(v, s, 64);
  return v;
}
__device__ __forceinline__ float wred_max(float v){
#pragma unroll
  for (int s=32; s>0; s>>=1) v = fmaxf(v, __shfl_xor(v, s, 64));
  return v;
}
__device__ __forceinline__ unsigned pack_bf16(float a, float b){
  unsigned short ua = __builtin_bit_cast(unsigned short, (__bf16)a);
  unsigned short ub = __builtin_bit_cast(unsigned short, (__bf16)b);
  return (unsigned)ua | ((unsigned)ub << 16);
}

// ---------------- prologue kernels ----------------
// packed gate row p = blk*16 + jj*4 + gate  <->  orig row gate*H + blk*4 + jj
__global__ void k_pack_enc(const float* __restrict__ wih, const float* __restrict__ whh,
                           const float* __restrict__ bih, const float* __restrict__ bhh,
                           __bf16* __restrict__ dst, float* __restrict__ bias){
  int p = blockIdx.x;
  int gate = p & 3, jj = (p >> 2) & 3, bq = p >> 4;
  int orig = gate*HH + bq*4 + jj;
  if (threadIdx.x == 0) bias[p] = bih[orig] + bhh[orig];
  const float* s0 = wih + (size_t)orig*DD;
  const float* s1 = whh + (size_t)orig*HH;
  __bf16* d = dst + (size_t)p*KENC;
  for (int k = threadIdx.x; k < KENC; k += blockDim.x)
    d[k] = (__bf16)(k < DD ? s0[k] : s1[k-DD]);
}
__global__ void k_pack_lstm(const float* __restrict__ wih, const float* __restrict__ whh,
                            const float* __restrict__ bih, const float* __restrict__ bhh,
                            __bf16* __restrict__ dst, float* __restrict__ bias){
  int p = blockIdx.x;
  int gate = p & 3, jj = (p >> 2) & 3, bq = p >> 4;
  int orig = gate*HH + bq*4 + jj;
  if (threadIdx.x == 0) bias[p] = bih[orig] + bhh[orig];
  const float* s0 = wih + (size_t)orig*HH;
  const float* s1 = whh + (size_t)orig*HH;
  __bf16* d = dst + (size_t)p*KLSTM;
  for (int k = threadIdx.x; k < KLSTM; k += blockDim.x)
    d[k] = (__bf16)(k < HH ? s0[k] : s1[k-HH]);
}
__global__ void k_conv(const float* __restrict__ src, __bf16* __restrict__ dst, int n){
  int i = blockIdx.x*blockDim.x + threadIdx.x;
  if (i < n) dst[i] = (__bf16)src[i];
}

// ---------------- encoder step: one dispatch per t ----------------
// 256 blocks x 256 thr (4 waves). Block owns 16 packed gate rows; wave wv
// computes m-tile wv (16 batches) over full K=1280.
__global__ __launch_bounds__(256)
void k_enc_step(const __bf16* __restrict__ demoC, const __bf16* __restrict__ wEnc,
                const float* __restrict__ bE, const __bf16* __restrict__ hR,
                __bf16* __restrict__ hW, __bf16* __restrict__ encB,
                float* __restrict__ cf, int t){
  const int bk = blockIdx.x, tid = threadIdx.x;
  const int wv = tid >> 6, ln = tid & 63;
  const int l15 = ln & 15, lhi = ln >> 4;
  const int klane = lhi * 8;
  const int am = wv*16 + l15;

  __shared__ float g_lds[BB*17];

  const __bf16* brow = wEnc + (size_t)(bk*16 + l15)*KENC;
  const __bf16* arow = demoC + ((size_t)am*LL + t)*DD;
  const __bf16* hrow = hR + (size_t)am*HH;

  f32x4 acc = {0.f,0.f,0.f,0.f};
#pragma unroll 8
  for (int kk = 0; kk < KENC; kk += 32) {
    int k0 = kk + klane;
    const __bf16* pa = (k0 < DD) ? (arow + k0) : (hrow + (k0 - DD));
    acc = __builtin_amdgcn_mfma_f32_16x16x32_bf16(*(const bf16x8*)pa,
                                                  *(const bf16x8*)(brow + k0), acc, 0,0,0);
  }
  {
    int r0 = wv*16 + lhi*4;
#pragma unroll
    for (int r = 0; r < 4; ++r) g_lds[(r0+r)*17 + l15] = acc[r];
  }
  __syncthreads();
  if (tid < 128) {
    const int m_ = tid >> 1, q2 = tid & 1;
    const int j0_ = bk*4 + 2*q2;
    int gb = m_*17 + q2*8, cb = bk*16 + q2*8;
    float gi0 = g_lds[gb+0]+bE[cb+0], gf0 = g_lds[gb+1]+bE[cb+1];
    float gg0 = g_lds[gb+2]+bE[cb+2], go0 = g_lds[gb+3]+bE[cb+3];
    float gi1 = g_lds[gb+4]+bE[cb+4], gf1 = g_lds[gb+5]+bE[cb+5];
    float gg1 = g_lds[gb+6]+bE[cb+6], go1 = g_lds[gb+7]+bE[cb+7];
    float cA = cf[m_*HH + j0_], cB = cf[m_*HH + j0_ + 1];
    float cn0 = sigm(gf0)*cA + sigm(gi0)*tanhf(gg0);
    float cn1 = sigm(gf1)*cB + sigm(gi1)*tanhf(gg1);
    float hn0 = sigm(go0)*tanhf(cn0);
    float hn1 = sigm(go1)*tanhf(cn1);
    cf[m_*HH + j0_] = cn0; cf[m_*HH + j0_ + 1] = cn1;
    unsigned hp = pack_bf16(hn0, hn1);
    *(unsigned*)(hW + (size_t)m_*HH + j0_) = hp;
    *(unsigned*)(encB + ((size_t)m_*LL + t)*HH + j0_) = hp;
  }
}

// ---------------- decoder step: one dispatch per t ----------------
// 256 blocks x 512 thr (8 waves): waves 0-3 K-half 0 (x part), 4-7 K-half 1 (h part).
__global__ __launch_bounds__(512)
void k_dec_step(const __bf16* __restrict__ xall, const __bf16* __restrict__ wLstm,
                const float* __restrict__ bL, const __bf16* __restrict__ hR,
                __bf16* __restrict__ hW, __bf16* __restrict__ hdec,
                float* __restrict__ cf, float* __restrict__ out, int t){
  const int bk = blockIdx.x, tid = threadIdx.x;
  const int wv = tid >> 6, ln = tid & 63;
  const int l15 = ln & 15, lhi = ln >> 4;
  const int klane = lhi * 8;
  const int mt = wv & 3;
  const int am = mt*16 + l15;
  const int khalf = wv >> 2;

  __shared__ float g_lds [BB*17];
  __shared__ float g_lds2[BB*17];

  const __bf16* brow = wLstm + (size_t)(bk*16 + l15)*KLSTM + khalf*HH;
  const __bf16* arow = khalf ? (hR + (size_t)am*HH)
                             : (xall + ((size_t)t*BB + am)*HH);

  f32x4 acc = {0.f,0.f,0.f,0.f};
#pragma unroll 8
  for (int kk = 0; kk < HH; kk += 32) {
    int k0 = kk + klane;
    acc = __builtin_amdgcn_mfma_f32_16x16x32_bf16(*(const bf16x8*)(arow + k0),
                                                  *(const bf16x8*)(brow + k0), acc, 0,0,0);
  }
  {
    float* gl = khalf ? g_lds2 : g_lds;
    int r0 = mt*16 + lhi*4;
#pragma unroll
    for (int r = 0; r < 4; ++r) gl[(r0+r)*17 + l15] = acc[r];
  }
  __syncthreads();
  if (tid < 128) {
    const int m_ = tid >> 1, q2 = tid & 1;
    const int j0_ = bk*4 + 2*q2;
    int gb = m_*17 + q2*8, cb = bk*16 + q2*8;
    float gi0 = g_lds[gb+0]+g_lds2[gb+0]+bL[cb+0], gf0 = g_lds[gb+1]+g_lds2[gb+1]+bL[cb+1];
    float gg0 = g_lds[gb+2]+g_lds2[gb+2]+bL[cb+2], go0 = g_lds[gb+3]+g_lds2[gb+3]+bL[cb+3];
    float gi1 = g_lds[gb+4]+g_lds2[gb+4]+bL[cb+4], gf1 = g_lds[gb+5]+g_lds2[gb+5]+bL[cb+5];
    float gg1 = g_lds[gb+6]+g_lds2[gb+6]+bL[cb+6], go1 = g_lds[gb+7]+g_lds2[gb+7]+bL[cb+7];
    float cA = cf[m_*HH + j0_], cB = cf[m_*HH + j0_ + 1];
    float cn0 = sigm(gf0)*cA + sigm(gi0)*tanhf(gg0);
    float cn1 = sigm(gf1)*cB + sigm(gi1)*tanhf(gg1);
    float hn0 = sigm(go0)*tanhf(cn0);
    float hn1 = sigm(go1)*tanhf(cn1);
    cf[m_*HH + j0_] = cn0; cf[m_*HH + j0_ + 1] = cn1;
    unsigned hp = pack_bf16(hn0, hn1);
    *(unsigned*)(hW + (size_t)m_*HH + j0_) = hp;
    *(unsigned*)(hdec + ((size_t)t*BB + m_)*HH + j0_) = hp;
    if (t == TT-1) {   // exact fp32 final h straight from registers
      out[QSZ + m_*HH + j0_]     = hn0;
      out[QSZ + m_*HH + j0_ + 1] = hn1;
    }
  }
}

// ---------------- static attention + decoder state init ----------------
// softmax is h-independent: scores = score_d[b,l] + (h.Wh)[b] -> per-row
// constant shift cancels. Attn weights shared across all decoder t.
__global__ __launch_bounds__(256)
void k_attn(const int* __restrict__ demlen, const float* __restrict__ h0,
            const float* __restrict__ c0, const float* __restrict__ attn_w,
            const __bf16* __restrict__ encB, __bf16* __restrict__ attnS,
            __bf16* __restrict__ hD0, float* __restrict__ cf){
  const int bk = blockIdx.x, tid = threadIdx.x;
  const int wv = tid >> 6, ln = tid & 63;
  __shared__ float sc_sh[LL];
  __shared__ float w_sh[LL];
  int b = bk >> 2, qq = bk & 3;
  for (int i = 0; i < 20; ++i) {
    int l = wv*20 + i;
    const __bf16* er = encB + ((size_t)b*LL + l)*HH + ln*16;
    bf16x8 e0 = *(const bf16x8*)(er);
    bf16x8 e1 = *(const bf16x8*)(er + 8);
    float part = 0.f;
#pragma unroll
    for (int j = 0; j < 8; ++j) {
      part += (float)e0[j] * attn_w[ln*16 + j];
      part += (float)e1[j] * attn_w[ln*16 + 8 + j];
    }
    part = wred_sum(part);
    if (ln == 0) sc_sh[l] = part;
  }
  __syncthreads();
  if (wv == 0) {
    int len = demlen[b];
    float s0 = (ln < len) ? sc_sh[ln] : -1e30f;
    float s1 = (ln < 16 && 64+ln < len) ? sc_sh[64+ln] : -1e30f;
    float mx = wred_max(fmaxf(s0, s1));
    float e0 = __expf(s0 - mx);
    float e1 = (ln < 16) ? __expf(s1 - mx) : 0.f;
    float inv = 1.f / wred_sum(e0 + e1);
    w_sh[ln] = e0 * inv;
    if (ln < 16) w_sh[64+ln] = e1 * inv;
  }
  __syncthreads();
  {
    int col = qq*256 + tid;
    float a = 0.f;
    const __bf16* eb = encB + (size_t)b*LL*HH + col;
#pragma unroll 4
    for (int l = 0; l < LL; ++l) a += w_sh[l] * (float)eb[(size_t)l*HH];
    attnS[(size_t)b*HH + col] = (__bf16)a;
  }
  // decoder state init (grid-stride)
  int gtid = bk*256 + tid;
  for (int i = gtid; i < BB*HH/2; i += 256*256) {
    int i2 = i*2;
    *((unsigned*)hD0 + i) = pack_bf16(h0[i2], h0[i2+1]);
  }
  for (int i = gtid; i < BB*HH; i += 256*256) cf[i] = c0[i];
}

// ---------------- phase X: x_all = relu([attn|obs_t] @ combW^T + b) --------
__global__ __launch_bounds__(256)
void k_x(const __bf16* __restrict__ attnS, const __bf16* __restrict__ stateB,
         const __bf16* __restrict__ wComb, const float* __restrict__ comb_b,
         __bf16* __restrict__ xall){
  const int bk = blockIdx.x, tid = threadIdx.x;
  const int wv = tid >> 6, ln = tid & 63;
  const int l15 = ln & 15, lhi = ln >> 4;
  const int klane = lhi * 8;
  int g = bk*4 + wv;
  for (int i = 0; i < 10; ++i) {
    int ti = i*1024 + g;            // 0..10239
    int mtt = ti >> 6, nt = ti & 63;
    f32x4 acc = {0.f,0.f,0.f,0.f};
    const __bf16* brow = wComb + (size_t)(nt*16 + l15)*KCOMB;
    int r = mtt*16 + l15, bb = r & 63;
    const __bf16* aat = attnS + (size_t)bb*HH;
    const __bf16* ast = stateB + (size_t)r*DD;
#pragma unroll 8
    for (int kk = 0; kk < KCOMB; kk += 32) {
      int k0 = kk + klane;
      bf16x8 af = (k0 < HH) ? *(const bf16x8*)(aat + k0)
                            : *(const bf16x8*)(ast + (k0-HH));
      acc = __builtin_amdgcn_mfma_f32_16x16x32_bf16(af, *(const bf16x8*)(brow + k0), acc, 0,0,0);
    }
    int col = nt*16 + l15;
    float cb = comb_b[col];
    int r0 = mtt*16 + lhi*4;
#pragma unroll
    for (int rr = 0; rr < 4; ++rr)
      xall[(size_t)(r0+rr)*HH + col] = (__bf16)fmaxf(acc[rr]+cb, 0.f);
  }
}

// ---------------- epilogue: m = hdec @ midW^T + mid_b ----------------
__global__ __launch_bounds__(256)
void k_mid(const __bf16* __restrict__ hdec, const __bf16* __restrict__ wMid,
           const float* __restrict__ mid_b, __bf16* __restrict__ mf){
  const int bk = blockIdx.x, tid = threadIdx.x;
  const int wv = tid >> 6, ln = tid & 63;
  const int l15 = ln & 15, lhi = ln >> 4;
  const int klane = lhi * 8;
  int g = bk*4 + wv;
  for (int i = 0; i < 10; ++i) {
    int ti = i*1024 + g;
    int mtt = ti >> 6, nt = ti & 63;
    f32x4 acc = {0.f,0.f,0.f,0.f};
    const __bf16* brow = wMid + (size_t)(nt*16 + l15)*HH;
    const __bf16* arow = hdec + (size_t)(mtt*16 + l15)*HH;
#pragma unroll 8
    for (int kk = 0; kk < HH; kk += 32) {
      int k0 = kk + klane;
      acc = __builtin_amdgcn_mfma_f32_16x16x32_bf16(*(const bf16x8*)(arow + k0),
                                                    *(const bf16x8*)(brow + k0), acc, 0,0,0);
    }
    int col = nt*16 + l15;
    float mb = mid_b[col];
    int r0 = mtt*16 + lhi*4;
#pragma unroll
    for (int rr = 0; rr < 4; ++rr)
      mf[(size_t)(r0+rr)*HH + col] = (__bf16)(acc[rr]+mb);
  }
}

// ---------------- q = mf @ outW^T + out_b ----------------
__global__ __launch_bounds__(256)
void k_out(const __bf16* __restrict__ mf, const float* __restrict__ out_w,
           const float* __restrict__ out_b, float* __restrict__ out){
  const int bk = blockIdx.x, tid = threadIdx.x;
  const int wv = tid >> 6, ln = tid & 63;
  int g = bk*4 + wv;
  for (int i = 0; i < 3; ++i) {
    int row = i*1024 + g;
    if (row < TT*BB) {
      const __bf16* mr = mf + (size_t)row*HH;
      float mreg[16];
#pragma unroll
      for (int k = 0; k < 16; ++k) mreg[k] = (float)mr[ln + 64*k];
      for (int a = 0; a < AA; ++a) {
        float p = 0.f;
#pragma unroll
        for (int k = 0; k < 16; ++k) p += mreg[k] * out_w[(size_t)a*HH + ln + 64*k];
        p = wred_sum(p);
        if (ln == 0) out[(size_t)row*AA + a] = p + out_b[a];
      }
    }
  }
}

// ---------------- final c copy ----------------
__global__ void k_fin(const float* __restrict__ cf, float* __restrict__ out){
  int i = blockIdx.x*blockDim.x + threadIdx.x;
  if (i < BB*HH) out[QSZ + BB*HH + i] = cf[i];
}

// ---------------- host launch ----------------
extern "C" void kernel_launch(void* const* d_in, const int* in_sizes, int n_in,
                              void* d_out, int out_size, void* d_ws, size_t ws_size,
                              hipStream_t stream) {
  (void)in_sizes; (void)n_in; (void)out_size; (void)ws_size;
  const float* state    = (const float*)d_in[0];
  const float* demo     = (const float*)d_in[1];
  const int*   demlen   = (const int*)d_in[2];
  const float* h0       = (const float*)d_in[3];
  const float* c0       = (const float*)d_in[4];
  const float* enc_wih  = (const float*)d_in[5];
  const float* enc_whh  = (const float*)d_in[6];
  const float* enc_bih  = (const float*)d_in[7];
  const float* enc_bhh  = (const float*)d_in[8];
  const float* attn_w   = (const float*)d_in[9];
  const float* comb_w   = (const float*)d_in[11];
  const float* comb_b   = (const float*)d_in[12];
  const float* lstm_wih = (const float*)d_in[13];
  const float* lstm_whh = (const float*)d_in[14];
  const float* lstm_bih = (const float*)d_in[15];
  const float* lstm_bhh = (const float*)d_in[16];
  const float* mid_w    = (const float*)d_in[17];
  const float* mid_b    = (const float*)d_in[18];
  const float* out_w    = (const float*)d_in[19];
  const float* out_b    = (const float*)d_in[20];
  char* ws = (char*)d_ws;

  __bf16* wEnc  = (__bf16*)(ws + OFF_WENC);
  __bf16* wLstm = (__bf16*)(ws + OFF_WLSTM);
  __bf16* wComb = (__bf16*)(ws + OFF_WCOMB);
  __bf16* wMid  = (__bf16*)(ws + OFF_WMID);
  float*  bE    = (float*)(ws + OFF_BIASE);
  float*  bL    = (float*)(ws + OFF_BIASL);
  __bf16* demoC = (__bf16*)(ws + OFF_DEMO);
  __bf16* stateB= (__bf16*)(ws + OFF_STATE);
  __bf16* encB  = (__bf16*)(ws + OFF_ENC);
  __bf16* hdec  = (__bf16*)(ws + OFF_HDEC);
  __bf16* xall  = (__bf16*)(ws + OFF_XALL);
  __bf16* mf    = (__bf16*)(ws + OFF_MF);
  __bf16* attnS = (__bf16*)(ws + OFF_ATTNS);
  float*  cf    = (float*)(ws + OFF_CF);
  __bf16* hbE0  = (__bf16*)(ws + OFF_HBUF);
  __bf16* hbE1  = hbE0 + (size_t)BB*HH;
  __bf16* hbD0  = hbE1 + (size_t)BB*HH;
  __bf16* hbD1  = hbD0 + (size_t)BB*HH;
  float*  out   = (float*)d_out;

  (void)hipMemsetAsync(cf,   0, (size_t)BB*HH*4, stream);   // enc c = 0
  (void)hipMemsetAsync(hbE0, 0, (size_t)BB*HH*2, stream);   // enc h = 0
  k_pack_enc <<<G4H, 256, 0, stream>>>(enc_wih, enc_whh, enc_bih, enc_bhh, wEnc, bE);
  k_pack_lstm<<<G4H, 256, 0, stream>>>(lstm_wih, lstm_whh, lstm_bih, lstm_bhh, wLstm, bL);
  k_conv<<<(HH*KCOMB + 255)/256, 256, 0, stream>>>(comb_w, wComb, HH*KCOMB);
  k_conv<<<(HH*HH   + 255)/256, 256, 0, stream>>>(mid_w,  wMid,  HH*HH);
  k_conv<<<(BB*LL*DD + 255)/256, 256, 0, stream>>>(demo,  demoC,  BB*LL*DD);
  k_conv<<<(TT*BB*DD + 255)/256, 256, 0, stream>>>(state, stateB, TT*BB*DD);

  for (int t = 0; t < LL; ++t) {
    __bf16* hR = (t & 1) ? hbE1 : hbE0;
    __bf16* hW = (t & 1) ? hbE0 : hbE1;
    k_enc_step<<<256, 256, 0, stream>>>(demoC, wEnc, bE, hR, hW, encB, cf, t);
  }
  k_attn<<<256, 256, 0, stream>>>(demlen, h0, c0, attn_w, encB, attnS, hbD0, cf);
  k_x<<<256, 256, 0, stream>>>(attnS, stateB, wComb, comb_b, xall);
  for (int t = 0; t < TT; ++t) {
    __bf16* hR = (t & 1) ? hbD1 : hbD0;
    __bf16* hW = (t & 1) ? hbD0 : hbD1;
    k_dec_step<<<256, 512, 0, stream>>>(xall, wLstm, bL, hR, hW, hdec, cf, out, t);
  }
  k_mid<<<256, 256, 0, stream>>>(hdec, wMid, mid_b, mf);
  k_out<<<256, 256, 0, stream>>>(mf, out_w, out_b, out);
  k_fin<<<(BB*HH + 255)/256, 256, 0, stream>>>(cf, out);
}

// Round 9
// 1908.755 us; speedup vs baseline: 2.7714x; 1.0034x over previous
//
#include <hip/hip_runtime.h>
#include <hip/hip_bf16.h>

// ---------------- problem dims ----------------
#define TT 40
#define BB 64
#define LL 80
#define DD 256
#define HH 1024
#define G4H 4096
#define AA 18
#define KENC 1280   // [demo(256) | h(1024)]
#define KLSTM 2048  // [x(1024) | h(1024)]
#define KCOMB 1280  // [attn(1024) | obs(256)]
#define QSZ (TT*BB*AA)

typedef __bf16 bf16x8 __attribute__((ext_vector_type(8)));
typedef float  f32x4  __attribute__((ext_vector_type(4)));

// ---------------- workspace layout (bytes) ----------------
#define OFF_WENC   ((size_t)0)
#define OFF_WLSTM  (OFF_WENC  + (size_t)G4H*KENC*2)
#define OFF_WCOMB  (OFF_WLSTM + (size_t)G4H*KLSTM*2)
#define OFF_WMID   (OFF_WCOMB + (size_t)HH*KCOMB*2)
#define OFF_BIASE  (OFF_WMID  + (size_t)HH*HH*2)
#define OFF_BIASL  (OFF_BIASE + (size_t)G4H*4)
#define OFF_DEMO   (OFF_BIASL + (size_t)G4H*4)
#define OFF_STATE  (OFF_DEMO  + (size_t)BB*LL*DD*2)
#define OFF_ENC    (OFF_STATE + (size_t)TT*BB*DD*2)
#define OFF_HDEC   (OFF_ENC   + (size_t)BB*LL*HH*2)
#define OFF_XALL   (OFF_HDEC  + (size_t)TT*BB*HH*2)
#define OFF_MF     (OFF_XALL  + (size_t)TT*BB*HH*2)
#define OFF_ATTNS  (OFF_MF    + (size_t)TT*BB*HH*2)
#define OFF_CF     (OFF_ATTNS + (size_t)BB*HH*2)
#define OFF_HBUF   (OFF_CF    + (size_t)BB*HH*4)   // 4 slots (encA,encB,decA,decB)

// ---------------- helpers ----------------
__device__ __forceinline__ float sigm(float x){ return 1.f/(1.f+__expf(-x)); }

__device__ __forceinline__ float wred_sum(float v){
#pragma unroll
  for (int s=32; s>0; s>>=1) v += __shfl_xor(v, s, 64);
  return v;
}
__device__ __forceinline__ float wred_max(float v){
#pragma unroll
  for (int s=32; s>0; s>>=1) v = fmaxf(v, __shfl_xor(v, s, 64));
  return v;
}
__device__ __forceinline__ unsigned pack_bf16(float a, float b){
  unsigned short ua = __builtin_bit_cast(unsigned short, (__bf16)a);
  unsigned short ub = __builtin_bit_cast(unsigned short, (__bf16)b);
  return (unsigned)ua | ((unsigned)ub << 16);
}

// ---------------- fused prologue (one dispatch) ----------------
// block ranges: [0,4096) pack enc | [4096,8192) pack lstm | [8192,13312) comb
// [13312,17408) mid | [17408,22528) demo | [22528,25088) state
// [25088,25344) zero cf | [25344,25472) zero hbE0
#define PB1 4096
#define PB2 8192
#define PB3 13312
#define PB4 17408
#define PB5 22528
#define PB6 25088
#define PB7 25344
#define PGRID 25472
__global__ __launch_bounds__(256)
void k_prep(const float* __restrict__ enc_wih, const float* __restrict__ enc_whh,
            const float* __restrict__ enc_bih, const float* __restrict__ enc_bhh,
            const float* __restrict__ lstm_wih, const float* __restrict__ lstm_whh,
            const float* __restrict__ lstm_bih, const float* __restrict__ lstm_bhh,
            const float* __restrict__ comb_w, const float* __restrict__ mid_w,
            const float* __restrict__ demo, const float* __restrict__ state,
            char* __restrict__ ws){
  int blk = blockIdx.x, tid = threadIdx.x;
  if (blk < PB1) {                    // pack enc: row p = blk*16+jj*4+gate? p == blk here
    int p = blk;
    int gate = p & 3, jj = (p >> 2) & 3, bq = p >> 4;
    int orig = gate*HH + bq*4 + jj;
    if (tid == 0) ((float*)(ws + OFF_BIASE))[p] = enc_bih[orig] + enc_bhh[orig];
    const float* s0 = enc_wih + (size_t)orig*DD;
    const float* s1 = enc_whh + (size_t)orig*HH;
    __bf16* d = (__bf16*)(ws + OFF_WENC) + (size_t)p*KENC;
    for (int k = tid; k < KENC; k += 256)
      d[k] = (__bf16)(k < DD ? s0[k] : s1[k-DD]);
  } else if (blk < PB2) {             // pack lstm
    int p = blk - PB1;
    int gate = p & 3, jj = (p >> 2) & 3, bq = p >> 4;
    int orig = gate*HH + bq*4 + jj;
    if (tid == 0) ((float*)(ws + OFF_BIASL))[p] = lstm_bih[orig] + lstm_bhh[orig];
    const float* s0 = lstm_wih + (size_t)orig*HH;
    const float* s1 = lstm_whh + (size_t)orig*HH;
    __bf16* d = (__bf16*)(ws + OFF_WLSTM) + (size_t)p*KLSTM;
    for (int k = tid; k < KLSTM; k += 256)
      d[k] = (__bf16)(k < HH ? s0[k] : s1[k-HH]);
  } else if (blk < PB3) {             // comb
    int i = (blk - PB2)*256 + tid;
    ((__bf16*)(ws + OFF_WCOMB))[i] = (__bf16)comb_w[i];
  } else if (blk < PB4) {             // mid
    int i = (blk - PB3)*256 + tid;
    ((__bf16*)(ws + OFF_WMID))[i] = (__bf16)mid_w[i];
  } else if (blk < PB5) {             // demo
    int i = (blk - PB4)*256 + tid;
    ((__bf16*)(ws + OFF_DEMO))[i] = (__bf16)demo[i];
  } else if (blk < PB6) {             // state
    int i = (blk - PB5)*256 + tid;
    ((__bf16*)(ws + OFF_STATE))[i] = (__bf16)state[i];
  } else if (blk < PB7) {             // zero cf
    int i = (blk - PB6)*256 + tid;
    ((float*)(ws + OFF_CF))[i] = 0.f;
  } else {                            // zero hbE0
    int i = (blk - PB7)*256 + tid;
    ((unsigned*)(ws + OFF_HBUF))[i] = 0u;
  }
}

// ---------------- encoder step: 256 blocks x 1024 thr (16 waves) ----------
// wave = (mt = wv&3, kq = wv>>2): m-tile mt, K-chunk kq*320..+320 of K=1280.
__global__ __launch_bounds__(1024)
void k_enc_step(const __bf16* __restrict__ demoC, const __bf16* __restrict__ wEnc,
                const float* __restrict__ bE, const __bf16* __restrict__ hR,
                __bf16* __restrict__ hW, __bf16* __restrict__ encB,
                float* __restrict__ cf, int t){
  const int bk = blockIdx.x, tid = threadIdx.x;
  const int wv = tid >> 6, ln = tid & 63;
  const int l15 = ln & 15, lhi = ln >> 4;
  const int klane = lhi * 8;
  const int mt = wv & 3, kq = wv >> 2;
  const int am = mt*16 + l15;

  __shared__ float g_lds[4][BB*17];

  const __bf16* brow = wEnc + (size_t)(bk*16 + l15)*KENC;
  const __bf16* arow = demoC + ((size_t)am*LL + t)*DD;
  const __bf16* hrow = hR + (size_t)am*HH;

  f32x4 acc = {0.f,0.f,0.f,0.f};
  const int kb = kq*320;
#pragma unroll
  for (int kk = 0; kk < 320; kk += 32) {
    int k0 = kb + kk + klane;
    const __bf16* pa = (k0 < DD) ? (arow + k0) : (hrow + (k0 - DD));
    acc = __builtin_amdgcn_mfma_f32_16x16x32_bf16(*(const bf16x8*)pa,
                                                  *(const bf16x8*)(brow + k0), acc, 0,0,0);
  }
  {
    int r0 = mt*16 + lhi*4;
#pragma unroll
    for (int r = 0; r < 4; ++r) g_lds[kq][(r0+r)*17 + l15] = acc[r];
  }
  __syncthreads();
  if (tid < 128) {
    const int m_ = tid >> 1, q2 = tid & 1;
    const int j0_ = bk*4 + 2*q2;
    int gb = m_*17 + q2*8, cb = bk*16 + q2*8;
    float g[8];
#pragma unroll
    for (int j = 0; j < 8; ++j)
      g[j] = g_lds[0][gb+j] + g_lds[1][gb+j] + g_lds[2][gb+j] + g_lds[3][gb+j] + bE[cb+j];
    float cA = cf[m_*HH + j0_], cB = cf[m_*HH + j0_ + 1];
    float cn0 = sigm(g[1])*cA + sigm(g[0])*tanhf(g[2]);
    float cn1 = sigm(g[5])*cB + sigm(g[4])*tanhf(g[6]);
    float hn0 = sigm(g[3])*tanhf(cn0);
    float hn1 = sigm(g[7])*tanhf(cn1);
    cf[m_*HH + j0_] = cn0; cf[m_*HH + j0_ + 1] = cn1;
    unsigned hp = pack_bf16(hn0, hn1);
    *(unsigned*)(hW + (size_t)m_*HH + j0_) = hp;
    *(unsigned*)(encB + ((size_t)m_*LL + t)*HH + j0_) = hp;
  }
}

// ---------------- decoder step: 256 blocks x 1024 thr (16 waves) ----------
// wave = (mt, kq): K-chunk kq*512..+512 of K=2048 (chunks 0-1 = x, 2-3 = h).
__global__ __launch_bounds__(1024)
void k_dec_step(const __bf16* __restrict__ xall, const __bf16* __restrict__ wLstm,
                const float* __restrict__ bL, const __bf16* __restrict__ hR,
                __bf16* __restrict__ hW, __bf16* __restrict__ hdec,
                float* __restrict__ cf, float* __restrict__ out, int t){
  const int bk = blockIdx.x, tid = threadIdx.x;
  const int wv = tid >> 6, ln = tid & 63;
  const int l15 = ln & 15, lhi = ln >> 4;
  const int klane = lhi * 8;
  const int mt = wv & 3, kq = wv >> 2;
  const int am = mt*16 + l15;

  __shared__ float g_lds[4][BB*17];

  const __bf16* brow = wLstm + (size_t)(bk*16 + l15)*KLSTM + kq*512;
  const __bf16* arow = (kq < 2) ? (xall + ((size_t)t*BB + am)*HH + kq*512)
                                : (hR + (size_t)am*HH + (kq-2)*512);

  f32x4 acc = {0.f,0.f,0.f,0.f};
#pragma unroll
  for (int kk = 0; kk < 512; kk += 32) {
    int k0 = kk + klane;
    acc = __builtin_amdgcn_mfma_f32_16x16x32_bf16(*(const bf16x8*)(arow + k0),
                                                  *(const bf16x8*)(brow + k0), acc, 0,0,0);
  }
  {
    int r0 = mt*16 + lhi*4;
#pragma unroll
    for (int r = 0; r < 4; ++r) g_lds[kq][(r0+r)*17 + l15] = acc[r];
  }
  __syncthreads();
  if (tid < 128) {
    const int m_ = tid >> 1, q2 = tid & 1;
    const int j0_ = bk*4 + 2*q2;
    int gb = m_*17 + q2*8, cb = bk*16 + q2*8;
    float g[8];
#pragma unroll
    for (int j = 0; j < 8; ++j)
      g[j] = g_lds[0][gb+j] + g_lds[1][gb+j] + g_lds[2][gb+j] + g_lds[3][gb+j] + bL[cb+j];
    float cA = cf[m_*HH + j0_], cB = cf[m_*HH + j0_ + 1];
    float cn0 = sigm(g[1])*cA + sigm(g[0])*tanhf(g[2]);
    float cn1 = sigm(g[5])*cB + sigm(g[4])*tanhf(g[6]);
    float hn0 = sigm(g[3])*tanhf(cn0);
    float hn1 = sigm(g[7])*tanhf(cn1);
    cf[m_*HH + j0_] = cn0; cf[m_*HH + j0_ + 1] = cn1;
    unsigned hp = pack_bf16(hn0, hn1);
    *(unsigned*)(hW + (size_t)m_*HH + j0_) = hp;
    *(unsigned*)(hdec + ((size_t)t*BB + m_)*HH + j0_) = hp;
    if (t == TT-1) {   // exact fp32 final h straight from registers
      out[QSZ + m_*HH + j0_]     = hn0;
      out[QSZ + m_*HH + j0_ + 1] = hn1;
    }
  }
}

// ---------------- static attention + decoder state init ----------------
// softmax is h-independent: scores = score_d[b,l] + (h.Wh)[b] -> per-row
// constant shift cancels. Attn weights shared across all decoder t.
__global__ __launch_bounds__(256)
void k_attn(const int* __restrict__ demlen, const float* __restrict__ h0,
            const float* __restrict__ c0, const float* __restrict__ attn_w,
            const __bf16* __restrict__ encB, __bf16* __restrict__ attnS,
            __bf16* __restrict__ hD0, float* __restrict__ cf){
  const int bk = blockIdx.x, tid = threadIdx.x;
  const int wv = tid >> 6, ln = tid & 63;
  __shared__ float sc_sh[LL];
  __shared__ float w_sh[LL];
  int b = bk >> 2, qq = bk & 3;
  for (int i = 0; i < 20; ++i) {
    int l = wv*20 + i;
    const __bf16* er = encB + ((size_t)b*LL + l)*HH + ln*16;
    bf16x8 e0 = *(const bf16x8*)(er);
    bf16x8 e1 = *(const bf16x8*)(er + 8);
    float part = 0.f;
#pragma unroll
    for (int j = 0; j < 8; ++j) {
      part += (float)e0[j] * attn_w[ln*16 + j];
      part += (float)e1[j] * attn_w[ln*16 + 8 + j];
    }
    part = wred_sum(part);
    if (ln == 0) sc_sh[l] = part;
  }
  __syncthreads();
  if (wv == 0) {
    int len = demlen[b];
    float s0 = (ln < len) ? sc_sh[ln] : -1e30f;
    float s1 = (ln < 16 && 64+ln < len) ? sc_sh[64+ln] : -1e30f;
    float mx = wred_max(fmaxf(s0, s1));
    float e0 = __expf(s0 - mx);
    float e1 = (ln < 16) ? __expf(s1 - mx) : 0.f;
    float inv = 1.f / wred_sum(e0 + e1);
    w_sh[ln] = e0 * inv;
    if (ln < 16) w_sh[64+ln] = e1 * inv;
  }
  __syncthreads();
  {
    int col = qq*256 + tid;
    float a = 0.f;
    const __bf16* eb = encB + (size_t)b*LL*HH + col;
#pragma unroll 4
    for (int l = 0; l < LL; ++l) a += w_sh[l] * (float)eb[(size_t)l*HH];
    attnS[(size_t)b*HH + col] = (__bf16)a;
  }
  // decoder state init (grid-stride)
  int gtid = bk*256 + tid;
  for (int i = gtid; i < BB*HH/2; i += 256*256) {
    int i2 = i*2;
    *((unsigned*)hD0 + i) = pack_bf16(h0[i2], h0[i2+1]);
  }
  for (int i = gtid; i < BB*HH; i += 256*256) cf[i] = c0[i];
}

// ---------------- phase X: x_all = relu([attn|obs_t] @ combW^T + b) --------
__global__ __launch_bounds__(256)
void k_x(const __bf16* __restrict__ attnS, const __bf16* __restrict__ stateB,
         const __bf16* __restrict__ wComb, const float* __restrict__ comb_b,
         __bf16* __restrict__ xall){
  const int bk = blockIdx.x, tid = threadIdx.x;
  const int wv = tid >> 6, ln = tid & 63;
  const int l15 = ln & 15, lhi = ln >> 4;
  const int klane = lhi * 8;
  int g = bk*4 + wv;
  for (int i = 0; i < 10; ++i) {
    int ti = i*1024 + g;            // 0..10239
    int mtt = ti >> 6, nt = ti & 63;
    f32x4 acc = {0.f,0.f,0.f,0.f};
    const __bf16* brow = wComb + (size_t)(nt*16 + l15)*KCOMB;
    int r = mtt*16 + l15, bb = r & 63;
    const __bf16* aat = attnS + (size_t)bb*HH;
    const __bf16* ast = stateB + (size_t)r*DD;
#pragma unroll 8
    for (int kk = 0; kk < KCOMB; kk += 32) {
      int k0 = kk + klane;
      bf16x8 af = (k0 < HH) ? *(const bf16x8*)(aat + k0)
                            : *(const bf16x8*)(ast + (k0-HH));
      acc = __builtin_amdgcn_mfma_f32_16x16x32_bf16(af, *(const bf16x8*)(brow + k0), acc, 0,0,0);
    }
    int col = nt*16 + l15;
    float cb = comb_b[col];
    int r0 = mtt*16 + lhi*4;
#pragma unroll
    for (int rr = 0; rr < 4; ++rr)
      xall[(size_t)(r0+rr)*HH + col] = (__bf16)fmaxf(acc[rr]+cb, 0.f);
  }
}

// ---------------- epilogue: m = hdec @ midW^T + mid_b ----------------
__global__ __launch_bounds__(256)
void k_mid(const __bf16* __restrict__ hdec, const __bf16* __restrict__ wMid,
           const float* __restrict__ mid_b, __bf16* __restrict__ mf){
  const int bk = blockIdx.x, tid = threadIdx.x;
  const int wv = tid >> 6, ln = tid & 63;
  const int l15 = ln & 15, lhi = ln >> 4;
  const int klane = lhi * 8;
  int g = bk*4 + wv;
  for (int i = 0; i < 10; ++i) {
    int ti = i*1024 + g;
    int mtt = ti >> 6, nt = ti & 63;
    f32x4 acc = {0.f,0.f,0.f,0.f};
    const __bf16* brow = wMid + (size_t)(nt*16 + l15)*HH;
    const __bf16* arow = hdec + (size_t)(mtt*16 + l15)*HH;
#pragma unroll 8
    for (int kk = 0; kk < HH; kk += 32) {
      int k0 = kk + klane;
      acc = __builtin_amdgcn_mfma_f32_16x16x32_bf16(*(const bf16x8*)(arow + k0),
                                                    *(const bf16x8*)(brow + k0), acc, 0,0,0);
    }
    int col = nt*16 + l15;
    float mb = mid_b[col];
    int r0 = mtt*16 + lhi*4;
#pragma unroll
    for (int rr = 0; rr < 4; ++rr)
      mf[(size_t)(r0+rr)*HH + col] = (__bf16)(acc[rr]+mb);
  }
}

// ---------------- q = mf @ outW^T + out_b ; final c copy ----------------
__global__ __launch_bounds__(256)
void k_out(const __bf16* __restrict__ mf, const float* __restrict__ out_w,
           const float* __restrict__ out_b, const float* __restrict__ cf,
           float* __restrict__ out){
  const int bk = blockIdx.x, tid = threadIdx.x;
  const int wv = tid >> 6, ln = tid & 63;
  int g = bk*4 + wv;
  for (int i = 0; i < 3; ++i) {
    int row = i*1024 + g;
    if (row < TT*BB) {
      const __bf16* mr = mf + (size_t)row*HH;
      float mreg[16];
#pragma unroll
      for (int k = 0; k < 16; ++k) mreg[k] = (float)mr[ln + 64*k];
      for (int a = 0; a < AA; ++a) {
        float p = 0.f;
#pragma unroll
        for (int k = 0; k < 16; ++k) p += mreg[k] * out_w[(size_t)a*HH + ln + 64*k];
        p = wred_sum(p);
        if (ln == 0) out[(size_t)row*AA + a] = p + out_b[a];
      }
    }
  }
  for (int i = bk*256 + tid; i < BB*HH; i += 256*256)
    out[QSZ + BB*HH + i] = cf[i];
}

// ---------------- host launch ----------------
extern "C" void kernel_launch(void* const* d_in, const int* in_sizes, int n_in,
                              void* d_out, int out_size, void* d_ws, size_t ws_size,
                              hipStream_t stream) {
  (void)in_sizes; (void)n_in; (void)out_size; (void)ws_size;
  const float* state    = (const float*)d_in[0];
  const float* demo     = (const float*)d_in[1];
  const int*   demlen   = (const int*)d_in[2];
  const float* h0       = (const float*)d_in[3];
  const float* c0       = (const float*)d_in[4];
  const float* enc_wih  = (const float*)d_in[5];
  const float* enc_whh  = (const float*)d_in[6];
  const float* enc_bih  = (const float*)d_in[7];
  const float* enc_bhh  = (const float*)d_in[8];
  const float* attn_w   = (const float*)d_in[9];
  const float* comb_w   = (const float*)d_in[11];
  const float* comb_b   = (const float*)d_in[12];
  const float* lstm_wih = (const float*)d_in[13];
  const float* lstm_whh = (const float*)d_in[14];
  const float* lstm_bih = (const float*)d_in[15];
  const float* lstm_bhh = (const float*)d_in[16];
  const float* mid_w    = (const float*)d_in[17];
  const float* mid_b    = (const float*)d_in[18];
  const float* out_w    = (const float*)d_in[19];
  const float* out_b    = (const float*)d_in[20];
  char* ws = (char*)d_ws;

  __bf16* wEnc  = (__bf16*)(ws + OFF_WENC);
  __bf16* wLstm = (__bf16*)(ws + OFF_WLSTM);
  __bf16* wComb = (__bf16*)(ws + OFF_WCOMB);
  __bf16* wMid  = (__bf16*)(ws + OFF_WMID);
  float*  bE    = (float*)(ws + OFF_BIASE);
  float*  bL    = (float*)(ws + OFF_BIASL);
  __bf16* demoC = (__bf16*)(ws + OFF_DEMO);
  __bf16* stateB= (__bf16*)(ws + OFF_STATE);
  __bf16* encB  = (__bf16*)(ws + OFF_ENC);
  __bf16* hdec  = (__bf16*)(ws + OFF_HDEC);
  __bf16* xall  = (__bf16*)(ws + OFF_XALL);
  __bf16* mf    = (__bf16*)(ws + OFF_MF);
  __bf16* attnS = (__bf16*)(ws + OFF_ATTNS);
  float*  cf    = (float*)(ws + OFF_CF);
  __bf16* hbE0  = (__bf16*)(ws + OFF_HBUF);
  __bf16* hbE1  = hbE0 + (size_t)BB*HH;
  __bf16* hbD0  = hbE1 + (size_t)BB*HH;
  __bf16* hbD1  = hbD0 + (size_t)BB*HH;
  float*  out   = (float*)d_out;

  k_prep<<<PGRID, 256, 0, stream>>>(enc_wih, enc_whh, enc_bih, enc_bhh,
                                    lstm_wih, lstm_whh, lstm_bih, lstm_bhh,
                                    comb_w, mid_w, demo, state, ws);
  for (int t = 0; t < LL; ++t) {
    __bf16* hR = (t & 1) ? hbE1 : hbE0;
    __bf16* hW = (t & 1) ? hbE0 : hbE1;
    k_enc_step<<<256, 1024, 0, stream>>>(demoC, wEnc, bE, hR, hW, encB, cf, t);
  }
  k_attn<<<256, 256, 0, stream>>>(demlen, h0, c0, attn_w, encB, attnS, hbD0, cf);
  k_x<<<256, 256, 0, stream>>>(attnS, stateB, wComb, comb_b, xall);
  for (int t = 0; t < TT; ++t) {
    __bf16* hR = (t & 1) ? hbD1 : hbD0;
    __bf16* hW = (t & 1) ? hbD0 : hbD1;
    k_dec_step<<<256, 1024, 0, stream>>>(xall, wLstm, bL, hR, hW, hdec, cf, out, t);
  }
  k_mid<<<256, 256, 0, stream>>>(hdec, wMid, mid_b, mf);
  k_out<<<256, 256, 0, stream>>>(mf, out_w, out_b, cf, out);
}